// Round 12
// baseline (379.306 us; speedup 1.0000x reference)
//
#include <hip/hip_runtime.h>
#include <hip/hip_bf16.h>

// VarianceAdaptor: 3x (conv1d->relu->LN->conv1d->relu->LN->linear) predictors,
// embedding adds between them, then length-regulate.
// Shapes fixed: B=32, S=512, D=F=512, K=3, T=4096, NB=256.
// Round 12: predictor chains are data-independent (emb adds use TRUTH inputs).
// prep computes X0,X1,X2 up front; convs batched into concurrent phases:
// {c1[0],c1[1]} -> {c2[0],c2[1],c1[2]} -> {c2[2]}. BK=32, LDS 72KB -> 2
// blocks/CU (4 waves/SIMD, m114 overlap). 5 dispatches total.

#define B_ 32
#define S_ 512
#define D_ 512
#define F_ 512
#define T_ 4096
#define SP_ 514           // padded rows per batch (row0 and row513 are zeros)
#define KK_ 1536          // 3*512 contraction length
#define NKT 48            // 1536/32 K-tiles
#define SLOT ((size_t)B_ * SP_ * D_)

typedef __attribute__((ext_vector_type(8))) short bf16x8;
typedef __attribute__((ext_vector_type(4))) float f32x4;

__device__ __forceinline__ float bf2f(unsigned short u) {
  union { unsigned int i; float f; } c; c.i = (unsigned int)u << 16; return c.f;
}
__device__ __forceinline__ unsigned short f2bf(float f) {
  __hip_bfloat16 h = __float2bfloat16(f);
  return *(unsigned short*)&h;
}

struct Job {
  const __hip_bfloat16* Pin;
  const __hip_bfloat16* WT;
  const float* bias;
  const float* g;
  const float* be;
  const float* wl;
  const float* bl;
  const unsigned char* mask;
  __hip_bfloat16* Pout;
  float* pred;
  int mode;                // 0: LN -> Pout (bf16 padded); 1: LN+linear -> pred
};

// ---- prep: wtrans (0..1151) | topad×3 (next 8224) | scan (last 32) ---------
#define WT_BLKS 1152
#define TP_BLKS 8224      // (16384 rows + 64 pad tasks) / 2
__global__ __launch_bounds__(256) void prep_k(const float* __restrict__ x,
                                              const float* __restrict__ W1,
                                              const float* __restrict__ W2,
                                              const int* __restrict__ dur,
                                              const float* __restrict__ ptruth,
                                              const float* __restrict__ pbins,
                                              const float* __restrict__ pemb,
                                              const float* __restrict__ etruth,
                                              const float* __restrict__ ebins,
                                              const float* __restrict__ eemb,
                                              __hip_bfloat16* __restrict__ X0,
                                              __hip_bfloat16* __restrict__ X1,
                                              __hip_bfloat16* __restrict__ X2,
                                              __hip_bfloat16* __restrict__ P0,
                                              __hip_bfloat16* __restrict__ P1,
                                              __hip_bfloat16* __restrict__ WT1,
                                              __hip_bfloat16* __restrict__ WT2,
                                              int* __restrict__ cum,
                                              float* __restrict__ mel_len) {
  const int blk = blockIdx.x;
  const int t = threadIdx.x;
  if (blk < WT_BLKS) {
    // ---- W [1536][512] fp32 -> WT [512][1536] bf16 (6 matrices) ----
    __shared__ float tb[64][65];
    const int w = blk / 192;
    const int kt = (blk % 192) >> 3;   // 24 kk-tiles of 64
    const int ft = blk & 7;            // 8 f-tiles of 64
    const float* src = (w < 3) ? (W1 + (size_t)w * KK_ * F_)
                               : (W2 + (size_t)(w - 3) * KK_ * F_);
    __hip_bfloat16* dst = (w < 3) ? (WT1 + (size_t)w * KK_ * F_)
                                  : (WT2 + (size_t)(w - 3) * KK_ * F_);
    const int ty = t >> 4, tx = t & 15;
    #pragma unroll
    for (int j = 0; j < 4; ++j) {
      const int r = ty + j * 16;       // kk within tile
      const float4 v = *(const float4*)(src + (size_t)(kt * 64 + r) * F_ + ft * 64 + tx * 4);
      tb[r][tx * 4 + 0] = v.x; tb[r][tx * 4 + 1] = v.y;
      tb[r][tx * 4 + 2] = v.z; tb[r][tx * 4 + 3] = v.w;
    }
    __syncthreads();
    #pragma unroll
    for (int j = 0; j < 4; ++j) {
      const int r = ty + j * 16;       // f within tile
      ushort4 u = make_ushort4(f2bf(tb[tx * 4 + 0][r]), f2bf(tb[tx * 4 + 1][r]),
                               f2bf(tb[tx * 4 + 2][r]), f2bf(tb[tx * 4 + 3][r]));
      *(ushort4*)((unsigned short*)dst + (size_t)(ft * 64 + r) * KK_ + kt * 64 + tx * 4) = u;
    }
  } else if (blk < WT_BLKS + TP_BLKS) {
    // ---- x -> X0; X1 = X0+pe; X2 = X1+ee (fp32 chains); pad zeroing ----
    __shared__ int i1s[2], i2s[2];
    const int half = t >> 7;           // 2 tasks per block
    const int tl = t & 127;
    const int task = (blk - WT_BLKS) * 2 + half;
    if (task < B_ * S_) {
      if (tl == 0) {
        float v = ptruth[task];
        int lo = 0, hi = 255;          // NB-1 bins, side='left'
        while (lo < hi) { const int mid = (lo + hi) >> 1; if (pbins[mid] < v) lo = mid + 1; else hi = mid; }
        i1s[half] = lo;
        v = etruth[task]; lo = 0; hi = 255;
        while (lo < hi) { const int mid = (lo + hi) >> 1; if (ebins[mid] < v) lo = mid + 1; else hi = mid; }
        i2s[half] = lo;
      }
      __syncthreads();
      const int b = task >> 9, s = task & 511;
      const size_t off = ((size_t)b * SP_ + s + 1) * D_ + tl * 4;
      const float4 v = *(const float4*)(x + (size_t)task * D_ + tl * 4);
      const float4 pe = *(const float4*)(pemb + (size_t)i1s[half] * D_ + tl * 4);
      const float4 ee = *(const float4*)(eemb + (size_t)i2s[half] * D_ + tl * 4);
      *(ushort4*)((unsigned short*)X0 + off) =
          make_ushort4(f2bf(v.x), f2bf(v.y), f2bf(v.z), f2bf(v.w));
      const float4 v1 = make_float4(v.x + pe.x, v.y + pe.y, v.z + pe.z, v.w + pe.w);
      *(ushort4*)((unsigned short*)X1 + off) =
          make_ushort4(f2bf(v1.x), f2bf(v1.y), f2bf(v1.z), f2bf(v1.w));
      *(ushort4*)((unsigned short*)X2 + off) =
          make_ushort4(f2bf(v1.x + ee.x), f2bf(v1.y + ee.y),
                       f2bf(v1.z + ee.z), f2bf(v1.w + ee.w));
    } else {
      __syncthreads();                 // keep barrier uniform across block
      const int idx = task - B_ * S_;  // 0..63 pad tasks
      const int b = idx >> 1;
      const int r = (idx & 1) ? (SP_ - 1) : 0;
      const size_t off = ((size_t)b * SP_ + r) * D_ + tl * 4;
      const ushort4 z = make_ushort4(0, 0, 0, 0);
      *(ushort4*)((unsigned short*)X0 + off) = z;   // also P2's pads (slot reuse)
      *(ushort4*)((unsigned short*)X1 + off) = z;
      *(ushort4*)((unsigned short*)X2 + off) = z;
      *(ushort4*)((unsigned short*)P0 + off) = z;
      *(ushort4*)((unsigned short*)P1 + off) = z;
    }
  } else {
    // ---- inclusive cumsum of durations (256 threads, 512 elems) ----
    __shared__ int sh[S_];
    const int b = blk - (WT_BLKS + TP_BLKS);
    sh[t] = dur[b * S_ + t];
    sh[t + 256] = dur[b * S_ + t + 256];
    __syncthreads();
    for (int off = 1; off < S_; off <<= 1) {
      const int a1 = (t >= off) ? sh[t - off] : 0;
      const int j2 = t + 256;
      const int a2 = (j2 >= off) ? sh[j2 - off] : 0;
      __syncthreads();
      sh[t] += a1; sh[j2] += a2;
      __syncthreads();
    }
    cum[b * S_ + t] = sh[t];
    cum[b * S_ + t + 256] = sh[t + 256];
    if (t == 255) mel_len[b] = (float)sh[S_ - 1];
  }
}

// ----- conv + bias + relu + LN (+ linear). Up to 3 independent jobs/grid.
// Y[b*512+st+i][f] = sum_kk Pin[b][st+i+(kk/512)][kk%512] * WT[f][kk]
__global__ __launch_bounds__(512, 4) void convfuse_k(Job j0, Job j1, Job j2) {
  extern __shared__ char smem[];
  char* As = smem;                     // 2 x 4096  [64 rows][64 B]
  char* Bs = smem + 2 * 4096;          // 2 x 32768 [512 f][64 B]
  const int pid = blockIdx.x >> 8;
  const Job jb = (pid == 0) ? j0 : (pid == 1 ? j1 : j2);
  // T1: per-job XCD swizzle over its 256 blocks.
  const int inner = blockIdx.x & 255;
  const int swz = (inner & 7) * 32 + (inner >> 3);
  const int b  = swz >> 3;             // 8 M-tiles per batch
  const int st = (swz & 7) * 64;
  const int t = threadIdx.x;
  const int lane = t & 63;
  const int wave = t >> 6;
  const int wn = wave * 64;            // wave's 64-col slice; all waves same rows

  f32x4 acc[4][4];
  #pragma unroll
  for (int m = 0; m < 4; ++m)
    #pragma unroll
    for (int n = 0; n < 4; ++n) acc[m][n] = (f32x4){0.f, 0.f, 0.f, 0.f};

  const __hip_bfloat16* Xb = jb.Pin + (size_t)b * SP_ * D_;
  const __hip_bfloat16* WT = jb.WT;

  // Stage one K=32 tile. A: 256 chunks (threads 0-255); B: 2048 chunks
  // (4/thread). T2 swizzle: source chunk ch^((row>>1)&3) -> 8 bank groups,
  // 2-way (free). LDS dest lane-linear (global_load_lds contract).
  auto stage = [&](int kt, int buf) {
    char* Ad = As + buf * 4096;
    if (t < 256) {
      const int row = t >> 2, ch = t & 3;
      const __hip_bfloat16* ga = Xb + (size_t)(st + (kt >> 4) + row) * D_ +
                                 (kt & 15) * 32 + (ch ^ ((row >> 1) & 3)) * 8;
      __builtin_amdgcn_global_load_lds(
          (const __attribute__((address_space(1))) void*)ga,
          (__attribute__((address_space(3))) void*)(Ad + t * 16), 16, 0, 0);
    }
    char* Bd = Bs + buf * 32768;
    #pragma unroll
    for (int i = 0; i < 4; ++i) {
      const int c = t + i * 512;
      const int fr = c >> 2, ch = c & 3;
      const __hip_bfloat16* gb = WT + (size_t)fr * KK_ + kt * 32 +
                                 (ch ^ ((fr >> 1) & 3)) * 8;
      __builtin_amdgcn_global_load_lds(
          (const __attribute__((address_space(1))) void*)gb,
          (__attribute__((address_space(3))) void*)(Bd + c * 16), 16, 0, 0);
    }
  };

  stage(0, 0);
  __syncthreads();
  const int rA = lane & 15;
  const int offx = ((lane >> 4) * 16) ^ (((rA >> 1) & 3) << 4);

  for (int kt = 0; kt < NKT; ++kt) {
    const int cur = kt & 1;
    if (kt < NKT - 1) stage(kt + 1, cur ^ 1);   // prefetch overlaps MFMA
    const char* Ab = As + cur * 4096;
    const char* Bb = Bs + cur * 32768;
    bf16x8 af[4], bf[4];
    #pragma unroll
    for (int m = 0; m < 4; ++m)
      af[m] = *(const bf16x8*)(Ab + (m * 16 + rA) * 64 + offx);
    #pragma unroll
    for (int n = 0; n < 4; ++n)
      bf[n] = *(const bf16x8*)(Bb + (wn + n * 16 + rA) * 64 + offx);
    __builtin_amdgcn_s_setprio(1);
    #pragma unroll
    for (int m = 0; m < 4; ++m)
      #pragma unroll
      for (int n = 0; n < 4; ++n)
        acc[m][n] = __builtin_amdgcn_mfma_f32_16x16x32_bf16(af[m], bf[n], acc[m][n], 0, 0, 0);
    __builtin_amdgcn_s_setprio(0);
    __syncthreads();                   // drains prefetch; sibling block covers
  }

  // ---------------- fused epilogue: bias + relu + LN (+ linear) --------------
  float* rS = (float*)smem;            // [8][64] row partial sums
  float* rQ = rS + 512;                // [8][64] row partial sumsq
  float* rP = rQ + 512;                // [8][64] row partial sum(v*g*wl)
  float* tS = rP + 512;                // [64] totals
  float* tQ = tS + 64;
  float* tP = tQ + 64;
  float* wG = tP + 64;                 // [8] per-wave sum g*wl
  float* wB = wG + 8;                  // [8] per-wave sum be*wl

  const int MODE = jb.mode;
  float bia[4], gg[4], bb[4], ww[4];
  #pragma unroll
  for (int n = 0; n < 4; ++n) {
    const int f = wn + n * 16 + rA;
    bia[n] = jb.bias[f]; gg[n] = jb.g[f]; bb[n] = jb.be[f];
    ww[n] = (MODE == 1) ? jb.wl[f] : 0.f;
  }
  if (MODE == 1) {
    float gwp = 0.f, bwp = 0.f;
    #pragma unroll
    for (int n = 0; n < 4; ++n) { gwp += gg[n] * ww[n]; bwp += bb[n] * ww[n]; }
    #pragma unroll
    for (int o = 1; o < 16; o <<= 1) {
      gwp += __shfl_xor(gwp, o); bwp += __shfl_xor(bwp, o);
    }
    if (lane == 0) { wG[wave] = gwp; wB[wave] = bwp; }
  }
  #pragma unroll
  for (int m = 0; m < 4; ++m) {
    #pragma unroll
    for (int r = 0; r < 4; ++r) {
      float sv = 0.f, sq = 0.f, sp = 0.f;
      #pragma unroll
      for (int n = 0; n < 4; ++n) {
        float v = fmaxf(acc[m][n][r] + bia[n], 0.f);
        acc[m][n][r] = v;
        sv += v; sq += v * v;
        sp += v * gg[n] * ww[n];
      }
      #pragma unroll
      for (int o = 1; o < 16; o <<= 1) {
        sv += __shfl_xor(sv, o); sq += __shfl_xor(sq, o);
        sp += __shfl_xor(sp, o);
      }
      if (rA == 0) {
        const int row = m * 16 + (lane >> 4) * 4 + r;
        rS[wave * 64 + row] = sv; rQ[wave * 64 + row] = sq;
        rP[wave * 64 + row] = sp;
      }
    }
  }
  __syncthreads();
  if (t < 64) {
    float S = 0.f, Q = 0.f, Pp = 0.f;
    #pragma unroll
    for (int w = 0; w < 8; ++w) {
      S += rS[w * 64 + t]; Q += rQ[w * 64 + t]; Pp += rP[w * 64 + t];
    }
    tS[t] = S; tQ[t] = Q; tP[t] = Pp;
  }
  __syncthreads();
  if (MODE == 0) {
    unsigned short* Pu = (unsigned short*)jb.Pout;
    #pragma unroll
    for (int m = 0; m < 4; ++m) {
      #pragma unroll
      for (int r = 0; r < 4; ++r) {
        const int row = m * 16 + (lane >> 4) * 4 + r;
        const float mean = tS[row] * (1.f / F_);
        const float var = tQ[row] * (1.f / F_) - mean * mean;
        const float inv = rsqrtf(var + 1e-5f);
        unsigned short* pp =
            Pu + ((size_t)b * SP_ + st + row + 1) * D_ + wn + rA;
        #pragma unroll
        for (int n = 0; n < 4; ++n)
          pp[n * 16] = f2bf((acc[m][n][r] - mean) * inv * gg[n] + bb[n]);
      }
    }
  } else {
    if (t < 64) {
      float GW = 0.f, BW = 0.f;
      #pragma unroll
      for (int w = 0; w < 8; ++w) { GW += wG[w]; BW += wB[w]; }
      const float mean = tS[t] * (1.f / F_);
      const float var = tQ[t] * (1.f / F_) - mean * mean;
      const float inv = rsqrtf(var + 1e-5f);
      const int grow = b * S_ + st + t;
      jb.pred[grow] = jb.mask[grow] ? 0.f
                                    : (inv * tP[t] - inv * mean * GW + BW + jb.bl[0]);
    }
  }
}

// --- length regulate (2 positions/block) + mel_mask -> float folded in ------
__global__ __launch_bounds__(256) void gather_k(const __hip_bfloat16* __restrict__ X,
                                                const int* __restrict__ cum,
                                                const unsigned char* __restrict__ melm,
                                                float* __restrict__ out,
                                                float* __restrict__ maskf) {
  const int b    = blockIdx.x >> 11;   // 2048 pairs per batch
  const int pos0 = (blockIdx.x & 2047) * 2;
  const int half = threadIdx.x >> 7;   // 0 or 1
  const int tl   = threadIdx.x & 127;
  const int pos  = pos0 + half;
  __shared__ int sidx[2], svalid[2];
  if (tl == 0) {
    const int* c = cum + b * S_;
    int lo = 0, hi = S_;
    while (lo < hi) {                  // upper_bound: first c[i] > pos
      const int mid = (lo + hi) >> 1;
      if (c[mid] <= pos) lo = mid + 1; else hi = mid;
    }
    sidx[half] = (lo < S_ - 1) ? lo : (S_ - 1);
    svalid[half] = (pos < c[S_ - 1]) ? 1 : 0;
    maskf[(size_t)b * T_ + pos] = melm[(size_t)b * T_ + pos] ? 1.f : 0.f;
  }
  __syncthreads();
  float4 v = make_float4(0.f, 0.f, 0.f, 0.f);
  if (svalid[half]) {
    const ushort4 u = *(const ushort4*)((const unsigned short*)X +
                        ((size_t)b * SP_ + sidx[half] + 1) * D_ + tl * 4);
    v = make_float4(bf2f(u.x), bf2f(u.y), bf2f(u.z), bf2f(u.w));
  }
  *(float4*)(out + ((size_t)b * T_ + pos) * D_ + tl * 4) = v;
}

extern "C" void kernel_launch(void* const* d_in, const int* in_sizes, int n_in,
                              void* d_out, int out_size, void* d_ws, size_t ws_size,
                              hipStream_t stream) {
  const float* x            = (const float*)d_in[0];
  const unsigned char* srcm = (const unsigned char*)d_in[1];
  const unsigned char* melm = (const unsigned char*)d_in[2];
  const float* pitch_truth  = (const float*)d_in[3];
  const float* energy_truth = (const float*)d_in[4];
  const int*   dur          = (const int*)d_in[5];
  const float* conv1_w = (const float*)d_in[6];
  const float* conv1_b = (const float*)d_in[7];
  const float* ln1_g   = (const float*)d_in[8];
  const float* ln1_b   = (const float*)d_in[9];
  const float* conv2_w = (const float*)d_in[10];
  const float* conv2_b = (const float*)d_in[11];
  const float* ln2_g   = (const float*)d_in[12];
  const float* ln2_b   = (const float*)d_in[13];
  const float* lin_w   = (const float*)d_in[14];
  const float* lin_b   = (const float*)d_in[15];
  const float* pitch_emb   = (const float*)d_in[16];
  const float* energy_emb  = (const float*)d_in[17];
  const float* pitch_bins  = (const float*)d_in[18];
  const float* energy_bins = (const float*)d_in[19];

  float* out      = (float*)d_out;
  float* x_out    = out;                               // 32*4096*512
  float* p_pitch  = out + (size_t)B_ * T_ * D_;
  float* p_energy = p_pitch + B_ * S_;
  float* p_dur    = p_energy + B_ * S_;
  float* p_mellen = p_dur + B_ * S_;
  float* p_mask   = p_mellen + B_;

  // ws slots (16.86MB padded bf16 each): S0=X0(later P2) S1=X1 S2=X2 S3=P0
  // S4=P1 | WT1 WT2 (4.7MB) | cum (64KB)   total ~93.7MB
  __hip_bfloat16* S0  = (__hip_bfloat16*)d_ws;
  __hip_bfloat16* S1  = S0 + SLOT;
  __hip_bfloat16* S2  = S1 + SLOT;
  __hip_bfloat16* S3  = S2 + SLOT;
  __hip_bfloat16* S4  = S3 + SLOT;
  __hip_bfloat16* WT1 = S4 + SLOT;
  __hip_bfloat16* WT2 = WT1 + (size_t)3 * F_ * KK_;
  int*  cum = (int*)(WT2 + (size_t)3 * F_ * KK_);

  const dim3 blk512t(512), blk256(256);
  const int convLds = 2 * (4096 + 32768);    // 72 KB -> 2 blocks/CU
  hipFuncSetAttribute((const void*)convfuse_k,
                      hipFuncAttributeMaxDynamicSharedMemorySize, convLds);

  prep_k<<<dim3(WT_BLKS + TP_BLKS + B_), blk256, 0, stream>>>(
      x, conv1_w, conv2_w, dur, pitch_truth, pitch_bins, pitch_emb,
      energy_truth, energy_bins, energy_emb,
      S0, S1, S2, S3, S4, WT1, WT2, cum, p_mellen);

  auto c1 = [&](int i, const __hip_bfloat16* in, __hip_bfloat16* Pout) {
    return Job{in, WT1 + (size_t)i * F_ * KK_, conv1_b + (size_t)i * F_,
               ln1_g + (size_t)i * F_, ln1_b + (size_t)i * F_,
               nullptr, nullptr, nullptr, Pout, nullptr, 0};
  };
  auto c2 = [&](int i, const __hip_bfloat16* in, float* pred) {
    return Job{in, WT2 + (size_t)i * F_ * KK_, conv2_b + (size_t)i * F_,
               ln2_g + (size_t)i * F_, ln2_b + (size_t)i * F_,
               lin_w + (size_t)i * F_, lin_b + i, srcm, nullptr, pred, 1};
  };

  // Phase 1: conv1 of predictors 0,1 (512 blocks, 2/CU)
  {
    Job a = c1(0, S0, S3), b = c1(1, S1, S4);
    convfuse_k<<<dim3(512), blk512t, convLds, stream>>>(a, b, b);
  }
  // Phase 2: conv2[0], conv2[1], conv1[2] (768 blocks)
  {
    Job a = c2(0, S3, p_pitch), b = c2(1, S4, p_energy), c = c1(2, S2, S0);
    convfuse_k<<<dim3(768), blk512t, convLds, stream>>>(a, b, c);
  }
  // Phase 3: conv2[2] (256 blocks)
  {
    Job a = c2(2, S0, p_dur);
    convfuse_k<<<dim3(256), blk512t, convLds, stream>>>(a, a, a);
  }

  gather_k<<<dim3(B_ * T_ / 2), blk256, 0, stream>>>(S2, cum, melm, x_out, p_mask);
}

// Round 13
// 320.195 us; speedup vs baseline: 1.1846x; 1.1846x over previous
//
#include <hip/hip_runtime.h>
#include <hip/hip_bf16.h>

// VarianceAdaptor: 3x (conv1d->relu->LN->conv1d->relu->LN->linear) predictors,
// embedding adds between them, then length-regulate.
// Shapes fixed: B=32, S=512, D=F=512, K=3, T=4096, NB=256.
// Round 13: conv -> faithful 8-phase counted-vmcnt template (T3+T4+T2+T5),
// BM=128 x BN=512, BK=64, 8 waves, LDS 160KB (1 block/CU), 2 jobs/dispatch
// (256 blocks). Quadrant order A0B0,A0B1,A1B1,A1B0; stages one half-tile per
// phase per last-use analysis; vmcnt(5) at phases 4 and 8 only. Fused
// bias+relu+LN(+linear) epilogue kept (block owns full 512-f rows).

#define B_ 32
#define S_ 512
#define D_ 512
#define F_ 512
#define T_ 4096
#define SP_ 514           // padded rows per batch (row0 and row513 are zeros)
#define KK_ 1536          // 3*512 contraction length
#define NITER 12          // 24 K-tiles of 64, 2 per iteration
#define SLOT ((size_t)B_ * SP_ * D_)

typedef __attribute__((ext_vector_type(8))) short bf16x8;
typedef __attribute__((ext_vector_type(4))) float f32x4;

__device__ __forceinline__ float bf2f(unsigned short u) {
  union { unsigned int i; float f; } c; c.i = (unsigned int)u << 16; return c.f;
}
__device__ __forceinline__ unsigned short f2bf(float f) {
  __hip_bfloat16 h = __float2bfloat16(f);
  return *(unsigned short*)&h;
}

struct Job {
  const __hip_bfloat16* Pin;
  const __hip_bfloat16* WT;
  const float* bias;
  const float* g;
  const float* be;
  const float* wl;
  const float* bl;
  const unsigned char* mask;
  __hip_bfloat16* Pout;
  float* pred;
  int mode;                // 0: LN -> Pout (bf16 padded); 1: LN+linear -> pred
};

// ---- prep: wtrans (0..1151) | topad×3 (next 8224) | scan (last 32) ---------
#define WT_BLKS 1152
#define TP_BLKS 8224      // (16384 rows + 64 pad tasks) / 2
__global__ __launch_bounds__(256) void prep_k(const float* __restrict__ x,
                                              const float* __restrict__ W1,
                                              const float* __restrict__ W2,
                                              const int* __restrict__ dur,
                                              const float* __restrict__ ptruth,
                                              const float* __restrict__ pbins,
                                              const float* __restrict__ pemb,
                                              const float* __restrict__ etruth,
                                              const float* __restrict__ ebins,
                                              const float* __restrict__ eemb,
                                              __hip_bfloat16* __restrict__ X0,
                                              __hip_bfloat16* __restrict__ X1,
                                              __hip_bfloat16* __restrict__ X2,
                                              __hip_bfloat16* __restrict__ P0,
                                              __hip_bfloat16* __restrict__ P1,
                                              __hip_bfloat16* __restrict__ WT1,
                                              __hip_bfloat16* __restrict__ WT2,
                                              int* __restrict__ cum,
                                              float* __restrict__ mel_len) {
  const int blk = blockIdx.x;
  const int t = threadIdx.x;
  if (blk < WT_BLKS) {
    __shared__ float tb[64][65];
    const int w = blk / 192;
    const int kt = (blk % 192) >> 3;   // 24 kk-tiles of 64
    const int ft = blk & 7;            // 8 f-tiles of 64
    const float* src = (w < 3) ? (W1 + (size_t)w * KK_ * F_)
                               : (W2 + (size_t)(w - 3) * KK_ * F_);
    __hip_bfloat16* dst = (w < 3) ? (WT1 + (size_t)w * KK_ * F_)
                                  : (WT2 + (size_t)(w - 3) * KK_ * F_);
    const int ty = t >> 4, tx = t & 15;
    #pragma unroll
    for (int j = 0; j < 4; ++j) {
      const int r = ty + j * 16;
      const float4 v = *(const float4*)(src + (size_t)(kt * 64 + r) * F_ + ft * 64 + tx * 4);
      tb[r][tx * 4 + 0] = v.x; tb[r][tx * 4 + 1] = v.y;
      tb[r][tx * 4 + 2] = v.z; tb[r][tx * 4 + 3] = v.w;
    }
    __syncthreads();
    #pragma unroll
    for (int j = 0; j < 4; ++j) {
      const int r = ty + j * 16;
      ushort4 u = make_ushort4(f2bf(tb[tx * 4 + 0][r]), f2bf(tb[tx * 4 + 1][r]),
                               f2bf(tb[tx * 4 + 2][r]), f2bf(tb[tx * 4 + 3][r]));
      *(ushort4*)((unsigned short*)dst + (size_t)(ft * 64 + r) * KK_ + kt * 64 + tx * 4) = u;
    }
  } else if (blk < WT_BLKS + TP_BLKS) {
    __shared__ int i1s[2], i2s[2];
    const int half = t >> 7;
    const int tl = t & 127;
    const int task = (blk - WT_BLKS) * 2 + half;
    if (task < B_ * S_) {
      if (tl == 0) {
        float v = ptruth[task];
        int lo = 0, hi = 255;
        while (lo < hi) { const int mid = (lo + hi) >> 1; if (pbins[mid] < v) lo = mid + 1; else hi = mid; }
        i1s[half] = lo;
        v = etruth[task]; lo = 0; hi = 255;
        while (lo < hi) { const int mid = (lo + hi) >> 1; if (ebins[mid] < v) lo = mid + 1; else hi = mid; }
        i2s[half] = lo;
      }
      __syncthreads();
      const int b = task >> 9, s = task & 511;
      const size_t off = ((size_t)b * SP_ + s + 1) * D_ + tl * 4;
      const float4 v = *(const float4*)(x + (size_t)task * D_ + tl * 4);
      const float4 pe = *(const float4*)(pemb + (size_t)i1s[half] * D_ + tl * 4);
      const float4 ee = *(const float4*)(eemb + (size_t)i2s[half] * D_ + tl * 4);
      *(ushort4*)((unsigned short*)X0 + off) =
          make_ushort4(f2bf(v.x), f2bf(v.y), f2bf(v.z), f2bf(v.w));
      const float4 v1 = make_float4(v.x + pe.x, v.y + pe.y, v.z + pe.z, v.w + pe.w);
      *(ushort4*)((unsigned short*)X1 + off) =
          make_ushort4(f2bf(v1.x), f2bf(v1.y), f2bf(v1.z), f2bf(v1.w));
      *(ushort4*)((unsigned short*)X2 + off) =
          make_ushort4(f2bf(v1.x + ee.x), f2bf(v1.y + ee.y),
                       f2bf(v1.z + ee.z), f2bf(v1.w + ee.w));
    } else {
      __syncthreads();
      const int idx = task - B_ * S_;
      const int b = idx >> 1;
      const int r = (idx & 1) ? (SP_ - 1) : 0;
      const size_t off = ((size_t)b * SP_ + r) * D_ + tl * 4;
      const ushort4 z = make_ushort4(0, 0, 0, 0);
      *(ushort4*)((unsigned short*)X0 + off) = z;   // X0 slot later reused as P2
      *(ushort4*)((unsigned short*)X1 + off) = z;
      *(ushort4*)((unsigned short*)X2 + off) = z;
      *(ushort4*)((unsigned short*)P0 + off) = z;
      *(ushort4*)((unsigned short*)P1 + off) = z;
    }
  } else {
    __shared__ int sh[S_];
    const int b = blk - (WT_BLKS + TP_BLKS);
    sh[t] = dur[b * S_ + t];
    sh[t + 256] = dur[b * S_ + t + 256];
    __syncthreads();
    for (int off = 1; off < S_; off <<= 1) {
      const int a1 = (t >= off) ? sh[t - off] : 0;
      const int j2 = t + 256;
      const int a2 = (j2 >= off) ? sh[j2 - off] : 0;
      __syncthreads();
      sh[t] += a1; sh[j2] += a2;
      __syncthreads();
    }
    cum[b * S_ + t] = sh[t];
    cum[b * S_ + t + 256] = sh[t + 256];
    if (t == 255) mel_len[b] = (float)sh[S_ - 1];
  }
}

// ---------------- 8-phase conv: 2 jobs x 128 blocks (BM=128, BN=512) --------
#define GLOAD(gptr, loff) __builtin_amdgcn_global_load_lds(                    \
    (const __attribute__((address_space(1))) void*)(gptr),                     \
    (__attribute__((address_space(3))) void*)(smem + (loff)), 16, 0, 0)

// One phase: quadrant (AH,BH) of the K-tile in dbuf D. 12 ds_read_b128,
// one half-tile stage, 2 barriers, 16 MFMA under setprio.
#define PHASE(D, AH, BH, STAGE_STMT, VM_STMT)                                  \
  {                                                                            \
    bf16x8 aR[2][2], bR[2][4];                                                 \
    const char* Ab = smem + (D) * 16384 + (AH) * 8192;                         \
    const char* Bb = smem + 32768 + (D) * 65536 + (BH) * 32768;                \
    _Pragma("unroll")                                                          \
    for (int kh = 0; kh < 2; ++kh) {                                           \
      _Pragma("unroll")                                                        \
      for (int mi = 0; mi < 2; ++mi) {                                         \
        const int row = rowbase + 16 * mi;                                     \
        aR[kh][mi] = *(const bf16x8*)(Ab + row * 128 +                         \
                                      (((kh * 4 + l4) ^ (row & 7)) * 16));     \
      }                                                                        \
      _Pragma("unroll")                                                        \
      for (int ni = 0; ni < 4; ++ni) {                                         \
        const int cl = colbase + 16 * ni;                                      \
        bR[kh][ni] = *(const bf16x8*)(Bb + cl * 128 +                          \
                                      (((kh * 4 + l4) ^ (cl & 7)) * 16));      \
      }                                                                        \
    }                                                                          \
    STAGE_STMT;                                                                \
    __builtin_amdgcn_s_barrier();                                              \
    asm volatile("s_waitcnt lgkmcnt(0)" ::: "memory");                         \
    __builtin_amdgcn_sched_barrier(0);                                         \
    __builtin_amdgcn_s_setprio(1);                                             \
    _Pragma("unroll")                                                          \
    for (int kh = 0; kh < 2; ++kh)                                             \
      _Pragma("unroll")                                                        \
      for (int mi = 0; mi < 2; ++mi)                                           \
        _Pragma("unroll")                                                      \
        for (int ni = 0; ni < 4; ++ni)                                         \
          acc[AH][BH][mi][ni] = __builtin_amdgcn_mfma_f32_16x16x32_bf16(       \
              aR[kh][mi], bR[kh][ni], acc[AH][BH][mi][ni], 0, 0, 0);           \
    __builtin_amdgcn_s_setprio(0);                                             \
    __builtin_amdgcn_sched_barrier(0);                                         \
    VM_STMT;                                                                   \
    __builtin_amdgcn_s_barrier();                                              \
  }

__global__ __launch_bounds__(512, 2) void conv8_k(Job j0, Job j1) {
  extern __shared__ char smem[];
  // LDS map: A [dbuf2][half2][64 rows][128B] @0 (32KB)
  //          B [dbuf2][half2][256 f][128B] @32768 (128KB)  total 160KB
  const Job jb = (blockIdx.x >> 7) ? j1 : j0;
  const int inner = blockIdx.x & 127;
  const int swz = (inner & 7) * 16 + (inner >> 3);  // XCD bijective (128=8*16)
  const int b  = swz >> 2;             // 4 M-tiles per batch
  const int st = (swz & 3) * 128;
  const int t = threadIdx.x;
  const int lane = t & 63;
  const int wave = t >> 6;
  const int wm2 = wave >> 2;           // 2 M wave-groups
  const int wn  = wave & 3;            // 4 N wave-groups
  const int rA = lane & 15;
  const int l4 = lane >> 4;
  const int rowbase = 32 * wm2 + rA;   // local row within A-half
  const int colbase = 64 * wn + rA;    // local col within B-half

  f32x4 acc[2][2][2][4];               // [ah][bh][mi][ni]
  #pragma unroll
  for (int a = 0; a < 2; ++a)
    #pragma unroll
    for (int c = 0; c < 2; ++c)
      #pragma unroll
      for (int m = 0; m < 2; ++m)
        #pragma unroll
        for (int n = 0; n < 4; ++n) acc[a][c][m][n] = (f32x4){0.f, 0.f, 0.f, 0.f};

  // half-tile stagers (wave-uniform load counts: A=1/thread, B=4/thread).
  // T2: source pre-swizzled ch^(row&7); LDS dest lane-linear (contract).
  auto stageA = [&](int kt, int half) {
    const int r = t >> 3, ch = t & 7;
    const __hip_bfloat16* ga = jb.Pin +
        ((size_t)b * SP_ + st + half * 64 + r + (kt >> 3)) * D_ +
        (kt & 7) * 64 + (ch ^ (r & 7)) * 8;
    GLOAD(ga, (kt & 1) * 16384 + half * 8192 + t * 16);
  };
  auto stageB = [&](int kt, int half) {
    #pragma unroll
    for (int i = 0; i < 4; ++i) {
      const int c = t + i * 512;
      const int fr = c >> 3, ch = c & 7;
      const __hip_bfloat16* gb = jb.WT +
          (size_t)(half * 256 + fr) * KK_ + kt * 64 + (ch ^ (fr & 7)) * 8;
      GLOAD(gb, 32768 + (kt & 1) * 65536 + half * 32768 + c * 16);
    }
  };

  // Prologue: tile0 fully (10 loads), tile1.A0 + tile1.B1 (5). vmcnt(5) -> t0 landed.
  stageA(0, 0); stageB(0, 0); stageA(0, 1); stageB(0, 1);
  stageA(1, 0); stageB(1, 1);
  asm volatile("s_waitcnt vmcnt(5)" ::: "memory");
  __builtin_amdgcn_s_barrier();

  for (int it = 0; it < NITER; ++it) {
    const int tk = 2 * it;             // even tile -> dbuf0, odd -> dbuf1
    const bool more = (it < NITER - 1);
    PHASE(0, 0, 0, { stageB(tk + 1, 0); }, );
    PHASE(0, 0, 1, { stageA(tk + 1, 1); }, );
    PHASE(0, 1, 1, { if (more) stageA(tk + 2, 0); }, );
    PHASE(0, 1, 0, { if (more) stageB(tk + 2, 1); },
          if (more) { asm volatile("s_waitcnt vmcnt(5)" ::: "memory"); }
          else      { asm volatile("s_waitcnt vmcnt(0)" ::: "memory"); });
    PHASE(1, 0, 0, { if (more) stageB(tk + 2, 0); }, );
    PHASE(1, 0, 1, { if (more) stageA(tk + 2, 1); }, );
    PHASE(1, 1, 1, { if (more) stageA(tk + 3, 0); }, );
    PHASE(1, 1, 0, { if (more) stageB(tk + 3, 1); },
          if (more) { asm volatile("s_waitcnt vmcnt(5)" ::: "memory"); }
          else      { asm volatile("s_waitcnt vmcnt(0)" ::: "memory"); });
  }

  // ---------------- fused epilogue: bias + relu + LN (+ linear) --------------
  float* rS = (float*)smem;            // [4 wn][128 rows]
  float* rQ = rS + 512;
  float* rP = rQ + 512;
  float* tS = rP + 512;                // [128]
  float* tQ = tS + 128;
  float* tP = tQ + 128;
  float* wG = tP + 128;                // [4]
  float* wB = wG + 4;

  const int MODE = jb.mode;
  float bia[2][4], gg[2][4], bb[2][4], ww[2][4];
  #pragma unroll
  for (int bh = 0; bh < 2; ++bh)
    #pragma unroll
    for (int ni = 0; ni < 4; ++ni) {
      const int f = 64 * wn + bh * 256 + 16 * ni + rA;
      bia[bh][ni] = jb.bias[f]; gg[bh][ni] = jb.g[f]; bb[bh][ni] = jb.be[f];
      ww[bh][ni] = (MODE == 1) ? jb.wl[f] : 0.f;
    }
  if (MODE == 1 && wm2 == 0) {
    float gwp = 0.f, bwp = 0.f;
    #pragma unroll
    for (int bh = 0; bh < 2; ++bh)
      #pragma unroll
      for (int ni = 0; ni < 4; ++ni) {
        gwp += gg[bh][ni] * ww[bh][ni]; bwp += bb[bh][ni] * ww[bh][ni];
      }
    #pragma unroll
    for (int o = 1; o < 16; o <<= 1) {
      gwp += __shfl_xor(gwp, o); bwp += __shfl_xor(bwp, o);
    }
    if (lane == 0) { wG[wn] = gwp; wB[wn] = bwp; }
  }
  #pragma unroll
  for (int ah = 0; ah < 2; ++ah)
    #pragma unroll
    for (int mi = 0; mi < 2; ++mi)
      #pragma unroll
      for (int reg = 0; reg < 4; ++reg) {
        float sv = 0.f, sq = 0.f, sp = 0.f;
        #pragma unroll
        for (int bh = 0; bh < 2; ++bh)
          #pragma unroll
          for (int ni = 0; ni < 4; ++ni) {
            float v = fmaxf(acc[ah][bh][mi][ni][reg] + bia[bh][ni], 0.f);
            acc[ah][bh][mi][ni][reg] = v;
            sv += v; sq += v * v;
            sp += v * gg[bh][ni] * ww[bh][ni];
          }
        #pragma unroll
        for (int o = 1; o < 16; o <<= 1) {
          sv += __shfl_xor(sv, o); sq += __shfl_xor(sq, o);
          sp += __shfl_xor(sp, o);
        }
        if (rA == 0) {
          const int lr = 64 * ah + 32 * wm2 + 16 * mi + l4 * 4 + reg;
          rS[wn * 128 + lr] = sv; rQ[wn * 128 + lr] = sq; rP[wn * 128 + lr] = sp;
        }
      }
  __syncthreads();
  if (t < 128) {
    float S = 0.f, Q = 0.f, Pp = 0.f;
    #pragma unroll
    for (int w = 0; w < 4; ++w) {
      S += rS[w * 128 + t]; Q += rQ[w * 128 + t]; Pp += rP[w * 128 + t];
    }
    tS[t] = S; tQ[t] = Q; tP[t] = Pp;
  }
  __syncthreads();
  if (MODE == 0) {
    unsigned short* Pu = (unsigned short*)jb.Pout;
    #pragma unroll
    for (int ah = 0; ah < 2; ++ah)
      #pragma unroll
      for (int mi = 0; mi < 2; ++mi)
        #pragma unroll
        for (int reg = 0; reg < 4; ++reg) {
          const int lr = 64 * ah + 32 * wm2 + 16 * mi + l4 * 4 + reg;
          const float mean = tS[lr] * (1.f / F_);
          const float var = tQ[lr] * (1.f / F_) - mean * mean;
          const float inv = rsqrtf(var + 1e-5f);
          unsigned short* pp = Pu + ((size_t)b * SP_ + st + lr + 1) * D_;
          #pragma unroll
          for (int bh = 0; bh < 2; ++bh)
            #pragma unroll
            for (int ni = 0; ni < 4; ++ni)
              pp[64 * wn + bh * 256 + 16 * ni + rA] =
                  f2bf((acc[ah][bh][mi][ni][reg] - mean) * inv * gg[bh][ni] + bb[bh][ni]);
        }
  } else {
    if (t < 128) {
      const float GW = wG[0] + wG[1] + wG[2] + wG[3];
      const float BW = wB[0] + wB[1] + wB[2] + wB[3];
      const float mean = tS[t] * (1.f / F_);
      const float var = tQ[t] * (1.f / F_) - mean * mean;
      const float inv = rsqrtf(var + 1e-5f);
      const int grow = b * S_ + st + t;
      jb.pred[grow] = jb.mask[grow] ? 0.f
                                    : (inv * tP[t] - inv * mean * GW + BW + jb.bl[0]);
    }
  }
}

// --- length regulate (2 positions/block) + mel_mask -> float folded in ------
__global__ __launch_bounds__(256) void gather_k(const __hip_bfloat16* __restrict__ X,
                                                const int* __restrict__ cum,
                                                const unsigned char* __restrict__ melm,
                                                float* __restrict__ out,
                                                float* __restrict__ maskf) {
  const int b    = blockIdx.x >> 11;
  const int pos0 = (blockIdx.x & 2047) * 2;
  const int half = threadIdx.x >> 7;
  const int tl   = threadIdx.x & 127;
  const int pos  = pos0 + half;
  __shared__ int sidx[2], svalid[2];
  if (tl == 0) {
    const int* c = cum + b * S_;
    int lo = 0, hi = S_;
    while (lo < hi) {
      const int mid = (lo + hi) >> 1;
      if (c[mid] <= pos) lo = mid + 1; else hi = mid;
    }
    sidx[half] = (lo < S_ - 1) ? lo : (S_ - 1);
    svalid[half] = (pos < c[S_ - 1]) ? 1 : 0;
    maskf[(size_t)b * T_ + pos] = melm[(size_t)b * T_ + pos] ? 1.f : 0.f;
  }
  __syncthreads();
  float4 v = make_float4(0.f, 0.f, 0.f, 0.f);
  if (svalid[half]) {
    const ushort4 u = *(const ushort4*)((const unsigned short*)X +
                        ((size_t)b * SP_ + sidx[half] + 1) * D_ + tl * 4);
    v = make_float4(bf2f(u.x), bf2f(u.y), bf2f(u.z), bf2f(u.w));
  }
  *(float4*)(out + ((size_t)b * T_ + pos) * D_ + tl * 4) = v;
}

extern "C" void kernel_launch(void* const* d_in, const int* in_sizes, int n_in,
                              void* d_out, int out_size, void* d_ws, size_t ws_size,
                              hipStream_t stream) {
  const float* x            = (const float*)d_in[0];
  const unsigned char* srcm = (const unsigned char*)d_in[1];
  const unsigned char* melm = (const unsigned char*)d_in[2];
  const float* pitch_truth  = (const float*)d_in[3];
  const float* energy_truth = (const float*)d_in[4];
  const int*   dur          = (const int*)d_in[5];
  const float* conv1_w = (const float*)d_in[6];
  const float* conv1_b = (const float*)d_in[7];
  const float* ln1_g   = (const float*)d_in[8];
  const float* ln1_b   = (const float*)d_in[9];
  const float* conv2_w = (const float*)d_in[10];
  const float* conv2_b = (const float*)d_in[11];
  const float* ln2_g   = (const float*)d_in[12];
  const float* ln2_b   = (const float*)d_in[13];
  const float* lin_w   = (const float*)d_in[14];
  const float* lin_b   = (const float*)d_in[15];
  const float* pitch_emb   = (const float*)d_in[16];
  const float* energy_emb  = (const float*)d_in[17];
  const float* pitch_bins  = (const float*)d_in[18];
  const float* energy_bins = (const float*)d_in[19];

  float* out      = (float*)d_out;
  float* x_out    = out;                               // 32*4096*512
  float* p_pitch  = out + (size_t)B_ * T_ * D_;
  float* p_energy = p_pitch + B_ * S_;
  float* p_dur    = p_energy + B_ * S_;
  float* p_mellen = p_dur + B_ * S_;
  float* p_mask   = p_mellen + B_;

  // ws slots (16.86MB padded bf16 each): S0=X0/P2, S1=X1, S2=X2, S3=P0, S4=P1
  // | WT1 WT2 (4.7MB each) | cum (64KB)   total ~93.7MB
  __hip_bfloat16* S0  = (__hip_bfloat16*)d_ws;
  __hip_bfloat16* S1  = S0 + SLOT;
  __hip_bfloat16* S2  = S1 + SLOT;
  __hip_bfloat16* S3  = S2 + SLOT;
  __hip_bfloat16* S4  = S3 + SLOT;
  __hip_bfloat16* WT1 = S4 + SLOT;
  __hip_bfloat16* WT2 = WT1 + (size_t)3 * F_ * KK_;
  int*  cum = (int*)(WT2 + (size_t)3 * F_ * KK_);

  const dim3 blk512t(512), blk256(256);
  const int convLds = 163840;                // 160 KB: full pool, 1 block/CU
  hipFuncSetAttribute((const void*)conv8_k,
                      hipFuncAttributeMaxDynamicSharedMemorySize, convLds);

  prep_k<<<dim3(WT_BLKS + TP_BLKS + B_), blk256, 0, stream>>>(
      x, conv1_w, conv2_w, dur, pitch_truth, pitch_bins, pitch_emb,
      energy_truth, energy_bins, energy_emb,
      S0, S1, S2, S3, S4, WT1, WT2, cum, p_mellen);

  auto c1 = [&](int i, const __hip_bfloat16* in, __hip_bfloat16* Pout) {
    return Job{in, WT1 + (size_t)i * F_ * KK_, conv1_b + (size_t)i * F_,
               ln1_g + (size_t)i * F_, ln1_b + (size_t)i * F_,
               nullptr, nullptr, nullptr, Pout, nullptr, 0};
  };
  auto c2 = [&](int i, const __hip_bfloat16* in, float* pred) {
    return Job{in, WT2 + (size_t)i * F_ * KK_, conv2_b + (size_t)i * F_,
               ln2_g + (size_t)i * F_, ln2_b + (size_t)i * F_,
               lin_w + (size_t)i * F_, lin_b + i, srcm, nullptr, pred, 1};
  };

  // D1: conv1[0], conv1[1]   (256 blocks = 1/CU)
  {
    Job a = c1(0, S0, S3), b = c1(1, S1, S4);
    conv8_k<<<dim3(256), blk512t, convLds, stream>>>(a, b);
  }
  // D2: conv2[0], conv1[2]   (P2 reuses S0 — X0 fully consumed in D1)
  {
    Job a = c2(0, S3, p_pitch), b = c1(2, S2, S0);
    conv8_k<<<dim3(256), blk512t, convLds, stream>>>(a, b);
  }
  // D3: conv2[1], conv2[2]
  {
    Job a = c2(1, S4, p_energy), b = c2(2, S0, p_dur);
    conv8_k<<<dim3(256), blk512t, convLds, stream>>>(a, b);
  }

  gather_k<<<dim3(B_ * T_ / 2), blk256, 0, stream>>>(S2, cum, melm, x_out, p_mask);
}

// Round 14
// 308.425 us; speedup vs baseline: 1.2298x; 1.0382x over previous
//
#include <hip/hip_runtime.h>
#include <hip/hip_bf16.h>

// VarianceAdaptor: 3x (conv1d->relu->LN->conv1d->relu->LN->linear) predictors,
// embedding adds between them, then length-regulate.
// Shapes fixed: B=32, S=512, D=F=512, K=3, T=4096, NB=256.
// Round 14: R13's 8-phase conv + operand-carrying ring (A0B0->A1B0->A1B1->
// A0B1): ds_read_b128 48 -> 24 per K-tile per wave (was 1.9x LDS-read-bound;
// now MFMA-bound). Stage slots & vmcnt(5) placement identical to R13.

#define B_ 32
#define S_ 512
#define D_ 512
#define F_ 512
#define T_ 4096
#define SP_ 514           // padded rows per batch (row0 and row513 are zeros)
#define KK_ 1536          // 3*512 contraction length
#define NITER 12          // 24 K-tiles of 64, 2 per iteration
#define SLOT ((size_t)B_ * SP_ * D_)

typedef __attribute__((ext_vector_type(8))) short bf16x8;
typedef __attribute__((ext_vector_type(4))) float f32x4;

__device__ __forceinline__ float bf2f(unsigned short u) {
  union { unsigned int i; float f; } c; c.i = (unsigned int)u << 16; return c.f;
}
__device__ __forceinline__ unsigned short f2bf(float f) {
  __hip_bfloat16 h = __float2bfloat16(f);
  return *(unsigned short*)&h;
}

struct Job {
  const __hip_bfloat16* Pin;
  const __hip_bfloat16* WT;
  const float* bias;
  const float* g;
  const float* be;
  const float* wl;
  const float* bl;
  const unsigned char* mask;
  __hip_bfloat16* Pout;
  float* pred;
  int mode;                // 0: LN -> Pout (bf16 padded); 1: LN+linear -> pred
};

// ---- prep: wtrans (0..1151) | topad×3 (next 8224) | scan (last 32) ---------
#define WT_BLKS 1152
#define TP_BLKS 8224      // (16384 rows + 64 pad tasks) / 2
__global__ __launch_bounds__(256) void prep_k(const float* __restrict__ x,
                                              const float* __restrict__ W1,
                                              const float* __restrict__ W2,
                                              const int* __restrict__ dur,
                                              const float* __restrict__ ptruth,
                                              const float* __restrict__ pbins,
                                              const float* __restrict__ pemb,
                                              const float* __restrict__ etruth,
                                              const float* __restrict__ ebins,
                                              const float* __restrict__ eemb,
                                              __hip_bfloat16* __restrict__ X0,
                                              __hip_bfloat16* __restrict__ X1,
                                              __hip_bfloat16* __restrict__ X2,
                                              __hip_bfloat16* __restrict__ P0,
                                              __hip_bfloat16* __restrict__ P1,
                                              __hip_bfloat16* __restrict__ WT1,
                                              __hip_bfloat16* __restrict__ WT2,
                                              int* __restrict__ cum,
                                              float* __restrict__ mel_len) {
  const int blk = blockIdx.x;
  const int t = threadIdx.x;
  if (blk < WT_BLKS) {
    __shared__ float tb[64][65];
    const int w = blk / 192;
    const int kt = (blk % 192) >> 3;   // 24 kk-tiles of 64
    const int ft = blk & 7;            // 8 f-tiles of 64
    const float* src = (w < 3) ? (W1 + (size_t)w * KK_ * F_)
                               : (W2 + (size_t)(w - 3) * KK_ * F_);
    __hip_bfloat16* dst = (w < 3) ? (WT1 + (size_t)w * KK_ * F_)
                                  : (WT2 + (size_t)(w - 3) * KK_ * F_);
    const int ty = t >> 4, tx = t & 15;
    #pragma unroll
    for (int j = 0; j < 4; ++j) {
      const int r = ty + j * 16;
      const float4 v = *(const float4*)(src + (size_t)(kt * 64 + r) * F_ + ft * 64 + tx * 4);
      tb[r][tx * 4 + 0] = v.x; tb[r][tx * 4 + 1] = v.y;
      tb[r][tx * 4 + 2] = v.z; tb[r][tx * 4 + 3] = v.w;
    }
    __syncthreads();
    #pragma unroll
    for (int j = 0; j < 4; ++j) {
      const int r = ty + j * 16;
      ushort4 u = make_ushort4(f2bf(tb[tx * 4 + 0][r]), f2bf(tb[tx * 4 + 1][r]),
                               f2bf(tb[tx * 4 + 2][r]), f2bf(tb[tx * 4 + 3][r]));
      *(ushort4*)((unsigned short*)dst + (size_t)(ft * 64 + r) * KK_ + kt * 64 + tx * 4) = u;
    }
  } else if (blk < WT_BLKS + TP_BLKS) {
    __shared__ int i1s[2], i2s[2];
    const int half = t >> 7;
    const int tl = t & 127;
    const int task = (blk - WT_BLKS) * 2 + half;
    if (task < B_ * S_) {
      if (tl == 0) {
        float v = ptruth[task];
        int lo = 0, hi = 255;
        while (lo < hi) { const int mid = (lo + hi) >> 1; if (pbins[mid] < v) lo = mid + 1; else hi = mid; }
        i1s[half] = lo;
        v = etruth[task]; lo = 0; hi = 255;
        while (lo < hi) { const int mid = (lo + hi) >> 1; if (ebins[mid] < v) lo = mid + 1; else hi = mid; }
        i2s[half] = lo;
      }
      __syncthreads();
      const int b = task >> 9, s = task & 511;
      const size_t off = ((size_t)b * SP_ + s + 1) * D_ + tl * 4;
      const float4 v = *(const float4*)(x + (size_t)task * D_ + tl * 4);
      const float4 pe = *(const float4*)(pemb + (size_t)i1s[half] * D_ + tl * 4);
      const float4 ee = *(const float4*)(eemb + (size_t)i2s[half] * D_ + tl * 4);
      *(ushort4*)((unsigned short*)X0 + off) =
          make_ushort4(f2bf(v.x), f2bf(v.y), f2bf(v.z), f2bf(v.w));
      const float4 v1 = make_float4(v.x + pe.x, v.y + pe.y, v.z + pe.z, v.w + pe.w);
      *(ushort4*)((unsigned short*)X1 + off) =
          make_ushort4(f2bf(v1.x), f2bf(v1.y), f2bf(v1.z), f2bf(v1.w));
      *(ushort4*)((unsigned short*)X2 + off) =
          make_ushort4(f2bf(v1.x + ee.x), f2bf(v1.y + ee.y),
                       f2bf(v1.z + ee.z), f2bf(v1.w + ee.w));
    } else {
      __syncthreads();
      const int idx = task - B_ * S_;
      const int b = idx >> 1;
      const int r = (idx & 1) ? (SP_ - 1) : 0;
      const size_t off = ((size_t)b * SP_ + r) * D_ + tl * 4;
      const ushort4 z = make_ushort4(0, 0, 0, 0);
      *(ushort4*)((unsigned short*)X0 + off) = z;   // X0 slot later reused as P2
      *(ushort4*)((unsigned short*)X1 + off) = z;
      *(ushort4*)((unsigned short*)X2 + off) = z;
      *(ushort4*)((unsigned short*)P0 + off) = z;
      *(ushort4*)((unsigned short*)P1 + off) = z;
    }
  } else {
    __shared__ int sh[S_];
    const int b = blk - (WT_BLKS + TP_BLKS);
    sh[t] = dur[b * S_ + t];
    sh[t + 256] = dur[b * S_ + t + 256];
    __syncthreads();
    for (int off = 1; off < S_; off <<= 1) {
      const int a1 = (t >= off) ? sh[t - off] : 0;
      const int j2 = t + 256;
      const int a2 = (j2 >= off) ? sh[j2 - off] : 0;
      __syncthreads();
      sh[t] += a1; sh[j2] += a2;
      __syncthreads();
    }
    cum[b * S_ + t] = sh[t];
    cum[b * S_ + t + 256] = sh[t + 256];
    if (t == 255) mel_len[b] = (float)sh[S_ - 1];
  }
}

// ---------------- 8-phase conv: 2 jobs x 128 blocks (BM=128, BN=512) --------
#define GLOAD(gptr, loff) __builtin_amdgcn_global_load_lds(                    \
    (const __attribute__((address_space(1))) void*)(gptr),                     \
    (__attribute__((address_space(3))) void*)(smem + (loff)), 16, 0, 0)

#define LOADA(dst, Dd, AHh)                                                    \
  _Pragma("unroll")                                                            \
  for (int kh = 0; kh < 2; ++kh)                                               \
    _Pragma("unroll")                                                          \
    for (int mi = 0; mi < 2; ++mi) {                                           \
      const int row = rowbase + 16 * mi;                                       \
      dst[kh][mi] = *(const bf16x8*)(smem + (Dd) * 16384 + (AHh) * 8192 +      \
                                     row * 128 + (((kh * 4 + l4) ^ (row & 7)) * 16)); \
    }

#define LOADB(Dd, BHh)                                                         \
  _Pragma("unroll")                                                            \
  for (int kh = 0; kh < 2; ++kh)                                               \
    _Pragma("unroll")                                                          \
    for (int ni = 0; ni < 4; ++ni) {                                           \
      const int cl = colbase + 16 * ni;                                        \
      bR[kh][ni] = *(const bf16x8*)(smem + 32768 + (Dd) * 65536 + (BHh) * 32768 + \
                                    cl * 128 + (((kh * 4 + l4) ^ (cl & 7)) * 16)); \
    }

// One phase: sync + 16 MFMA on (AREG, bR) into acc[AH][BH]. Loads for the
// phase are issued by the caller BEFORE invoking PH (or carried in regs).
#define PH(AREG, AH, BH, STAGE_STMT, VM_STMT)                                  \
  {                                                                            \
    STAGE_STMT;                                                                \
    __builtin_amdgcn_s_barrier();                                              \
    asm volatile("s_waitcnt lgkmcnt(0)" ::: "memory");                         \
    __builtin_amdgcn_sched_barrier(0);                                         \
    __builtin_amdgcn_s_setprio(1);                                             \
    _Pragma("unroll")                                                          \
    for (int kh = 0; kh < 2; ++kh)                                             \
      _Pragma("unroll")                                                        \
      for (int mi = 0; mi < 2; ++mi)                                           \
        _Pragma("unroll")                                                      \
        for (int ni = 0; ni < 4; ++ni)                                         \
          acc[AH][BH][mi][ni] = __builtin_amdgcn_mfma_f32_16x16x32_bf16(       \
              AREG[kh][mi], bR[kh][ni], acc[AH][BH][mi][ni], 0, 0, 0);         \
    __builtin_amdgcn_s_setprio(0);                                             \
    __builtin_amdgcn_sched_barrier(0);                                         \
    VM_STMT;                                                                   \
    __builtin_amdgcn_s_barrier();                                              \
  }

__global__ __launch_bounds__(512, 2) void conv8_k(Job j0, Job j1) {
  extern __shared__ char smem[];
  // LDS map: A [dbuf2][half2][64 rows][128B] @0 (32KB)
  //          B [dbuf2][half2][256 f][128B] @32768 (128KB)  total 160KB
  const Job jb = (blockIdx.x >> 7) ? j1 : j0;
  const int inner = blockIdx.x & 127;
  const int swz = (inner & 7) * 16 + (inner >> 3);  // XCD bijective (128=8*16)
  const int b  = swz >> 2;             // 4 M-tiles per batch
  const int st = (swz & 3) * 128;
  const int t = threadIdx.x;
  const int lane = t & 63;
  const int wave = t >> 6;
  const int wm2 = wave >> 2;           // 2 M wave-groups
  const int wn  = wave & 3;            // 4 N wave-groups
  const int rA = lane & 15;
  const int l4 = lane >> 4;
  const int rowbase = 32 * wm2 + rA;   // local row within A-half
  const int colbase = 64 * wn + rA;    // local col within B-half

  f32x4 acc[2][2][2][4];               // [ah][bh][mi][ni]
  #pragma unroll
  for (int a = 0; a < 2; ++a)
    #pragma unroll
    for (int c = 0; c < 2; ++c)
      #pragma unroll
      for (int m = 0; m < 2; ++m)
        #pragma unroll
        for (int n = 0; n < 4; ++n) acc[a][c][m][n] = (f32x4){0.f, 0.f, 0.f, 0.f};

  // half-tile stagers (wave-uniform load counts: A=1/thread, B=4/thread).
  auto stageA = [&](int kt, int half) {
    const int r = t >> 3, ch = t & 7;
    const __hip_bfloat16* ga = jb.Pin +
        ((size_t)b * SP_ + st + half * 64 + r + (kt >> 3)) * D_ +
        (kt & 7) * 64 + (ch ^ (r & 7)) * 8;
    GLOAD(ga, (kt & 1) * 16384 + half * 8192 + t * 16);
  };
  auto stageB = [&](int kt, int half) {
    #pragma unroll
    for (int i = 0; i < 4; ++i) {
      const int c = t + i * 512;
      const int fr = c >> 3, ch = c & 7;
      const __hip_bfloat16* gb = jb.WT +
          (size_t)(half * 256 + fr) * KK_ + kt * 64 + (ch ^ (fr & 7)) * 8;
      GLOAD(gb, 32768 + (kt & 1) * 65536 + half * 32768 + c * 16);
    }
  };

  // Prologue: tile0 fully (10 loads), tile1.A0 + tile1.B1 (5). vmcnt(5) -> t0 landed.
  stageA(0, 0); stageB(0, 0); stageA(0, 1); stageB(0, 1);
  stageA(1, 0); stageB(1, 1);
  asm volatile("s_waitcnt vmcnt(5)" ::: "memory");
  __builtin_amdgcn_s_barrier();

  bf16x8 aR0[2][2], aR1[2][2], bR[2][4];

  for (int it = 0; it < NITER; ++it) {
    const int tk = 2 * it;             // even tile -> dbuf0, odd -> dbuf1
    const bool more = (it < NITER - 1);
    // ---- dbuf0, tile tk: ring A0B0 -> A1B0 -> A1B1 -> A0B1 ----
    LOADA(aR0, 0, 0); LOADB(0, 0);                       // 12 reads
    PH(aR0, 0, 0, { stageB(tk + 1, 0); }, );
    LOADA(aR1, 0, 1);                                    // 4 reads (carry bR=B0)
    PH(aR1, 1, 0, { stageA(tk + 1, 1); }, );
    LOADB(0, 1);                                         // 8 reads (carry aR1)
    PH(aR1, 1, 1, { if (more) stageA(tk + 2, 0); }, );
    // no reads: carry aR0 (from ph1) + bR (B1 from ph3)
    PH(aR0, 0, 1, { if (more) stageB(tk + 2, 1); },
       if (more) { asm volatile("s_waitcnt vmcnt(5)" ::: "memory"); }
       else      { asm volatile("s_waitcnt vmcnt(0)" ::: "memory"); });
    // ---- dbuf1, tile tk+1: same ring ----
    LOADA(aR0, 1, 0); LOADB(1, 0);
    PH(aR0, 0, 0, { if (more) stageB(tk + 2, 0); }, );
    LOADA(aR1, 1, 1);
    PH(aR1, 1, 0, { if (more) stageA(tk + 2, 1); }, );
    LOADB(1, 1);
    PH(aR1, 1, 1, { if (more) stageA(tk + 3, 0); }, );
    PH(aR0, 0, 1, { if (more) stageB(tk + 3, 1); },
       if (more) { asm volatile("s_waitcnt vmcnt(5)" ::: "memory"); }
       else      { asm volatile("s_waitcnt vmcnt(0)" ::: "memory"); });
  }

  // ---------------- fused epilogue: bias + relu + LN (+ linear) --------------
  float* rS = (float*)smem;            // [4 wn][128 rows]
  float* rQ = rS + 512;
  float* rP = rQ + 512;
  float* tS = rP + 512;                // [128]
  float* tQ = tS + 128;
  float* tP = tQ + 128;
  float* wG = tP + 128;                // [4]
  float* wB = wG + 4;

  const int MODE = jb.mode;
  float bia[2][4], gg[2][4], bb[2][4], ww[2][4];
  #pragma unroll
  for (int bh = 0; bh < 2; ++bh)
    #pragma unroll
    for (int ni = 0; ni < 4; ++ni) {
      const int f = 64 * wn + bh * 256 + 16 * ni + rA;
      bia[bh][ni] = jb.bias[f]; gg[bh][ni] = jb.g[f]; bb[bh][ni] = jb.be[f];
      ww[bh][ni] = (MODE == 1) ? jb.wl[f] : 0.f;
    }
  if (MODE == 1 && wm2 == 0) {
    float gwp = 0.f, bwp = 0.f;
    #pragma unroll
    for (int bh = 0; bh < 2; ++bh)
      #pragma unroll
      for (int ni = 0; ni < 4; ++ni) {
        gwp += gg[bh][ni] * ww[bh][ni]; bwp += bb[bh][ni] * ww[bh][ni];
      }
    #pragma unroll
    for (int o = 1; o < 16; o <<= 1) {
      gwp += __shfl_xor(gwp, o); bwp += __shfl_xor(bwp, o);
    }
    if (lane == 0) { wG[wn] = gwp; wB[wn] = bwp; }
  }
  #pragma unroll
  for (int ah = 0; ah < 2; ++ah)
    #pragma unroll
    for (int mi = 0; mi < 2; ++mi)
      #pragma unroll
      for (int reg = 0; reg < 4; ++reg) {
        float sv = 0.f, sq = 0.f, sp = 0.f;
        #pragma unroll
        for (int bh = 0; bh < 2; ++bh)
          #pragma unroll
          for (int ni = 0; ni < 4; ++ni) {
            float v = fmaxf(acc[ah][bh][mi][ni][reg] + bia[bh][ni], 0.f);
            acc[ah][bh][mi][ni][reg] = v;
            sv += v; sq += v * v;
            sp += v * gg[bh][ni] * ww[bh][ni];
          }
        #pragma unroll
        for (int o = 1; o < 16; o <<= 1) {
          sv += __shfl_xor(sv, o); sq += __shfl_xor(sq, o);
          sp += __shfl_xor(sp, o);
        }
        if (rA == 0) {
          const int lr = 64 * ah + 32 * wm2 + 16 * mi + l4 * 4 + reg;
          rS[wn * 128 + lr] = sv; rQ[wn * 128 + lr] = sq; rP[wn * 128 + lr] = sp;
        }
      }
  __syncthreads();
  if (t < 128) {
    float S = 0.f, Q = 0.f, Pp = 0.f;
    #pragma unroll
    for (int w = 0; w < 4; ++w) {
      S += rS[w * 128 + t]; Q += rQ[w * 128 + t]; Pp += rP[w * 128 + t];
    }
    tS[t] = S; tQ[t] = Q; tP[t] = Pp;
  }
  __syncthreads();
  if (MODE == 0) {
    unsigned short* Pu = (unsigned short*)jb.Pout;
    #pragma unroll
    for (int ah = 0; ah < 2; ++ah)
      #pragma unroll
      for (int mi = 0; mi < 2; ++mi)
        #pragma unroll
        for (int reg = 0; reg < 4; ++reg) {
          const int lr = 64 * ah + 32 * wm2 + 16 * mi + l4 * 4 + reg;
          const float mean = tS[lr] * (1.f / F_);
          const float var = tQ[lr] * (1.f / F_) - mean * mean;
          const float inv = rsqrtf(var + 1e-5f);
          unsigned short* pp = Pu + ((size_t)b * SP_ + st + lr + 1) * D_;
          #pragma unroll
          for (int bh = 0; bh < 2; ++bh)
            #pragma unroll
            for (int ni = 0; ni < 4; ++ni)
              pp[64 * wn + bh * 256 + 16 * ni + rA] =
                  f2bf((acc[ah][bh][mi][ni][reg] - mean) * inv * gg[bh][ni] + bb[bh][ni]);
        }
  } else {
    if (t < 128) {
      const float GW = wG[0] + wG[1] + wG[2] + wG[3];
      const float BW = wB[0] + wB[1] + wB[2] + wB[3];
      const float mean = tS[t] * (1.f / F_);
      const float var = tQ[t] * (1.f / F_) - mean * mean;
      const float inv = rsqrtf(var + 1e-5f);
      const int grow = b * S_ + st + t;
      jb.pred[grow] = jb.mask[grow] ? 0.f
                                    : (inv * tP[t] - inv * mean * GW + BW + jb.bl[0]);
    }
  }
}

// --- length regulate (2 positions/block) + mel_mask -> float folded in ------
__global__ __launch_bounds__(256) void gather_k(const __hip_bfloat16* __restrict__ X,
                                                const int* __restrict__ cum,
                                                const unsigned char* __restrict__ melm,
                                                float* __restrict__ out,
                                                float* __restrict__ maskf) {
  const int b    = blockIdx.x >> 11;
  const int pos0 = (blockIdx.x & 2047) * 2;
  const int half = threadIdx.x >> 7;
  const int tl   = threadIdx.x & 127;
  const int pos  = pos0 + half;
  __shared__ int sidx[2], svalid[2];
  if (tl == 0) {
    const int* c = cum + b * S_;
    int lo = 0, hi = S_;
    while (lo < hi) {
      const int mid = (lo + hi) >> 1;
      if (c[mid] <= pos) lo = mid + 1; else hi = mid;
    }
    sidx[half] = (lo < S_ - 1) ? lo : (S_ - 1);
    svalid[half] = (pos < c[S_ - 1]) ? 1 : 0;
    maskf[(size_t)b * T_ + pos] = melm[(size_t)b * T_ + pos] ? 1.f : 0.f;
  }
  __syncthreads();
  float4 v = make_float4(0.f, 0.f, 0.f, 0.f);
  if (svalid[half]) {
    const ushort4 u = *(const ushort4*)((const unsigned short*)X +
                        ((size_t)b * SP_ + sidx[half] + 1) * D_ + tl * 4);
    v = make_float4(bf2f(u.x), bf2f(u.y), bf2f(u.z), bf2f(u.w));
  }
  *(float4*)(out + ((size_t)b * T_ + pos) * D_ + tl * 4) = v;
}

extern "C" void kernel_launch(void* const* d_in, const int* in_sizes, int n_in,
                              void* d_out, int out_size, void* d_ws, size_t ws_size,
                              hipStream_t stream) {
  const float* x            = (const float*)d_in[0];
  const unsigned char* srcm = (const unsigned char*)d_in[1];
  const unsigned char* melm = (const unsigned char*)d_in[2];
  const float* pitch_truth  = (const float*)d_in[3];
  const float* energy_truth = (const float*)d_in[4];
  const int*   dur          = (const int*)d_in[5];
  const float* conv1_w = (const float*)d_in[6];
  const float* conv1_b = (const float*)d_in[7];
  const float* ln1_g   = (const float*)d_in[8];
  const float* ln1_b   = (const float*)d_in[9];
  const float* conv2_w = (const float*)d_in[10];
  const float* conv2_b = (const float*)d_in[11];
  const float* ln2_g   = (const float*)d_in[12];
  const float* ln2_b   = (const float*)d_in[13];
  const float* lin_w   = (const float*)d_in[14];
  const float* lin_b   = (const float*)d_in[15];
  const float* pitch_emb   = (const float*)d_in[16];
  const float* energy_emb  = (const float*)d_in[17];
  const float* pitch_bins  = (const float*)d_in[18];
  const float* energy_bins = (const float*)d_in[19];

  float* out      = (float*)d_out;
  float* x_out    = out;                               // 32*4096*512
  float* p_pitch  = out + (size_t)B_ * T_ * D_;
  float* p_energy = p_pitch + B_ * S_;
  float* p_dur    = p_energy + B_ * S_;
  float* p_mellen = p_dur + B_ * S_;
  float* p_mask   = p_mellen + B_;

  // ws slots (16.86MB padded bf16 each): S0=X0/P2, S1=X1, S2=X2, S3=P0, S4=P1
  // | WT1 WT2 (4.7MB each) | cum (64KB)   total ~93.7MB
  __hip_bfloat16* S0  = (__hip_bfloat16*)d_ws;
  __hip_bfloat16* S1  = S0 + SLOT;
  __hip_bfloat16* S2  = S1 + SLOT;
  __hip_bfloat16* S3  = S2 + SLOT;
  __hip_bfloat16* S4  = S3 + SLOT;
  __hip_bfloat16* WT1 = S4 + SLOT;
  __hip_bfloat16* WT2 = WT1 + (size_t)3 * F_ * KK_;
  int*  cum = (int*)(WT2 + (size_t)3 * F_ * KK_);

  const dim3 blk512t(512), blk256(256);
  const int convLds = 163840;                // 160 KB: full pool, 1 block/CU
  hipFuncSetAttribute((const void*)conv8_k,
                      hipFuncAttributeMaxDynamicSharedMemorySize, convLds);

  prep_k<<<dim3(WT_BLKS + TP_BLKS + B_), blk256, 0, stream>>>(
      x, conv1_w, conv2_w, dur, pitch_truth, pitch_bins, pitch_emb,
      energy_truth, energy_bins, energy_emb,
      S0, S1, S2, S3, S4, WT1, WT2, cum, p_mellen);

  auto c1 = [&](int i, const __hip_bfloat16* in, __hip_bfloat16* Pout) {
    return Job{in, WT1 + (size_t)i * F_ * KK_, conv1_b + (size_t)i * F_,
               ln1_g + (size_t)i * F_, ln1_b + (size_t)i * F_,
               nullptr, nullptr, nullptr, Pout, nullptr, 0};
  };
  auto c2 = [&](int i, const __hip_bfloat16* in, float* pred) {
    return Job{in, WT2 + (size_t)i * F_ * KK_, conv2_b + (size_t)i * F_,
               ln2_g + (size_t)i * F_, ln2_b + (size_t)i * F_,
               lin_w + (size_t)i * F_, lin_b + i, srcm, nullptr, pred, 1};
  };

  // D1: conv1[0], conv1[1]   (256 blocks = 1/CU)
  {
    Job a = c1(0, S0, S3), b = c1(1, S1, S4);
    conv8_k<<<dim3(256), blk512t, convLds, stream>>>(a, b);
  }
  // D2: conv2[0], conv1[2]   (P2 reuses S0 — X0 fully consumed in D1)
  {
    Job a = c2(0, S3, p_pitch), b = c1(2, S2, S0);
    conv8_k<<<dim3(256), blk512t, convLds, stream>>>(a, b);
  }
  // D3: conv2[1], conv2[2]
  {
    Job a = c2(1, S4, p_energy), b = c2(2, S0, p_dur);
    conv8_k<<<dim3(256), blk512t, convLds, stream>>>(a, b);
  }

  gather_k<<<dim3(B_ * T_ / 2), blk256, 0, stream>>>(S2, cum, melm, x_out, p_mask);
}

// Round 15
// 308.389 us; speedup vs baseline: 1.2300x; 1.0001x over previous
//
#include <hip/hip_runtime.h>
#include <hip/hip_bf16.h>

// VarianceAdaptor: 3x (conv1d->relu->LN->conv1d->relu->LN->linear) predictors,
// embedding adds between them, then length-regulate.
// Shapes fixed: B=32, S=512, D=F=512, K=3, T=4096, NB=256.
// Round 15: R14 with ONE change: conv __launch_bounds__(512,2) -> (512,1).
// The ",2" (min waves/EU) capped VGPR at 128; the loop needs ~185 (acc=128 +
// carried operands 32 + addressing) -> ~60-reg inner-loop scratch spill, the
// ~3x stall R13/R14 showed. VGPR<=256 keeps 8 waves/CU (2/SIMD, m69) which is
// the LDS-set occupancy anyway. Everything else bit-identical to R14.

#define B_ 32
#define S_ 512
#define D_ 512
#define F_ 512
#define T_ 4096
#define SP_ 514           // padded rows per batch (row0 and row513 are zeros)
#define KK_ 1536          // 3*512 contraction length
#define NITER 12          // 24 K-tiles of 64, 2 per iteration
#define SLOT ((size_t)B_ * SP_ * D_)

typedef __attribute__((ext_vector_type(8))) short bf16x8;
typedef __attribute__((ext_vector_type(4))) float f32x4;

__device__ __forceinline__ float bf2f(unsigned short u) {
  union { unsigned int i; float f; } c; c.i = (unsigned int)u << 16; return c.f;
}
__device__ __forceinline__ unsigned short f2bf(float f) {
  __hip_bfloat16 h = __float2bfloat16(f);
  return *(unsigned short*)&h;
}

struct Job {
  const __hip_bfloat16* Pin;
  const __hip_bfloat16* WT;
  const float* bias;
  const float* g;
  const float* be;
  const float* wl;
  const float* bl;
  const unsigned char* mask;
  __hip_bfloat16* Pout;
  float* pred;
  int mode;                // 0: LN -> Pout (bf16 padded); 1: LN+linear -> pred
};

// ---- prep: wtrans (0..1151) | topad×3 (next 8224) | scan (last 32) ---------
#define WT_BLKS 1152
#define TP_BLKS 8224      // (16384 rows + 64 pad tasks) / 2
__global__ __launch_bounds__(256) void prep_k(const float* __restrict__ x,
                                              const float* __restrict__ W1,
                                              const float* __restrict__ W2,
                                              const int* __restrict__ dur,
                                              const float* __restrict__ ptruth,
                                              const float* __restrict__ pbins,
                                              const float* __restrict__ pemb,
                                              const float* __restrict__ etruth,
                                              const float* __restrict__ ebins,
                                              const float* __restrict__ eemb,
                                              __hip_bfloat16* __restrict__ X0,
                                              __hip_bfloat16* __restrict__ X1,
                                              __hip_bfloat16* __restrict__ X2,
                                              __hip_bfloat16* __restrict__ P0,
                                              __hip_bfloat16* __restrict__ P1,
                                              __hip_bfloat16* __restrict__ WT1,
                                              __hip_bfloat16* __restrict__ WT2,
                                              int* __restrict__ cum,
                                              float* __restrict__ mel_len) {
  const int blk = blockIdx.x;
  const int t = threadIdx.x;
  if (blk < WT_BLKS) {
    __shared__ float tb[64][65];
    const int w = blk / 192;
    const int kt = (blk % 192) >> 3;   // 24 kk-tiles of 64
    const int ft = blk & 7;            // 8 f-tiles of 64
    const float* src = (w < 3) ? (W1 + (size_t)w * KK_ * F_)
                               : (W2 + (size_t)(w - 3) * KK_ * F_);
    __hip_bfloat16* dst = (w < 3) ? (WT1 + (size_t)w * KK_ * F_)
                                  : (WT2 + (size_t)(w - 3) * KK_ * F_);
    const int ty = t >> 4, tx = t & 15;
    #pragma unroll
    for (int j = 0; j < 4; ++j) {
      const int r = ty + j * 16;
      const float4 v = *(const float4*)(src + (size_t)(kt * 64 + r) * F_ + ft * 64 + tx * 4);
      tb[r][tx * 4 + 0] = v.x; tb[r][tx * 4 + 1] = v.y;
      tb[r][tx * 4 + 2] = v.z; tb[r][tx * 4 + 3] = v.w;
    }
    __syncthreads();
    #pragma unroll
    for (int j = 0; j < 4; ++j) {
      const int r = ty + j * 16;
      ushort4 u = make_ushort4(f2bf(tb[tx * 4 + 0][r]), f2bf(tb[tx * 4 + 1][r]),
                               f2bf(tb[tx * 4 + 2][r]), f2bf(tb[tx * 4 + 3][r]));
      *(ushort4*)((unsigned short*)dst + (size_t)(ft * 64 + r) * KK_ + kt * 64 + tx * 4) = u;
    }
  } else if (blk < WT_BLKS + TP_BLKS) {
    __shared__ int i1s[2], i2s[2];
    const int half = t >> 7;
    const int tl = t & 127;
    const int task = (blk - WT_BLKS) * 2 + half;
    if (task < B_ * S_) {
      if (tl == 0) {
        float v = ptruth[task];
        int lo = 0, hi = 255;
        while (lo < hi) { const int mid = (lo + hi) >> 1; if (pbins[mid] < v) lo = mid + 1; else hi = mid; }
        i1s[half] = lo;
        v = etruth[task]; lo = 0; hi = 255;
        while (lo < hi) { const int mid = (lo + hi) >> 1; if (ebins[mid] < v) lo = mid + 1; else hi = mid; }
        i2s[half] = lo;
      }
      __syncthreads();
      const int b = task >> 9, s = task & 511;
      const size_t off = ((size_t)b * SP_ + s + 1) * D_ + tl * 4;
      const float4 v = *(const float4*)(x + (size_t)task * D_ + tl * 4);
      const float4 pe = *(const float4*)(pemb + (size_t)i1s[half] * D_ + tl * 4);
      const float4 ee = *(const float4*)(eemb + (size_t)i2s[half] * D_ + tl * 4);
      *(ushort4*)((unsigned short*)X0 + off) =
          make_ushort4(f2bf(v.x), f2bf(v.y), f2bf(v.z), f2bf(v.w));
      const float4 v1 = make_float4(v.x + pe.x, v.y + pe.y, v.z + pe.z, v.w + pe.w);
      *(ushort4*)((unsigned short*)X1 + off) =
          make_ushort4(f2bf(v1.x), f2bf(v1.y), f2bf(v1.z), f2bf(v1.w));
      *(ushort4*)((unsigned short*)X2 + off) =
          make_ushort4(f2bf(v1.x + ee.x), f2bf(v1.y + ee.y),
                       f2bf(v1.z + ee.z), f2bf(v1.w + ee.w));
    } else {
      __syncthreads();
      const int idx = task - B_ * S_;
      const int b = idx >> 1;
      const int r = (idx & 1) ? (SP_ - 1) : 0;
      const size_t off = ((size_t)b * SP_ + r) * D_ + tl * 4;
      const ushort4 z = make_ushort4(0, 0, 0, 0);
      *(ushort4*)((unsigned short*)X0 + off) = z;   // X0 slot later reused as P2
      *(ushort4*)((unsigned short*)X1 + off) = z;
      *(ushort4*)((unsigned short*)X2 + off) = z;
      *(ushort4*)((unsigned short*)P0 + off) = z;
      *(ushort4*)((unsigned short*)P1 + off) = z;
    }
  } else {
    __shared__ int sh[S_];
    const int b = blk - (WT_BLKS + TP_BLKS);
    sh[t] = dur[b * S_ + t];
    sh[t + 256] = dur[b * S_ + t + 256];
    __syncthreads();
    for (int off = 1; off < S_; off <<= 1) {
      const int a1 = (t >= off) ? sh[t - off] : 0;
      const int j2 = t + 256;
      const int a2 = (j2 >= off) ? sh[j2 - off] : 0;
      __syncthreads();
      sh[t] += a1; sh[j2] += a2;
      __syncthreads();
    }
    cum[b * S_ + t] = sh[t];
    cum[b * S_ + t + 256] = sh[t + 256];
    if (t == 255) mel_len[b] = (float)sh[S_ - 1];
  }
}

// ---------------- 8-phase conv: 2 jobs x 128 blocks (BM=128, BN=512) --------
#define GLOAD(gptr, loff) __builtin_amdgcn_global_load_lds(                    \
    (const __attribute__((address_space(1))) void*)(gptr),                     \
    (__attribute__((address_space(3))) void*)(smem + (loff)), 16, 0, 0)

#define LOADA(dst, Dd, AHh)                                                    \
  _Pragma("unroll")                                                            \
  for (int kh = 0; kh < 2; ++kh)                                               \
    _Pragma("unroll")                                                          \
    for (int mi = 0; mi < 2; ++mi) {                                           \
      const int row = rowbase + 16 * mi;                                       \
      dst[kh][mi] = *(const bf16x8*)(smem + (Dd) * 16384 + (AHh) * 8192 +      \
                                     row * 128 + (((kh * 4 + l4) ^ (row & 7)) * 16)); \
    }

#define LOADB(Dd, BHh)                                                         \
  _Pragma("unroll")                                                            \
  for (int kh = 0; kh < 2; ++kh)                                               \
    _Pragma("unroll")                                                          \
    for (int ni = 0; ni < 4; ++ni) {                                           \
      const int cl = colbase + 16 * ni;                                        \
      bR[kh][ni] = *(const bf16x8*)(smem + 32768 + (Dd) * 65536 + (BHh) * 32768 + \
                                    cl * 128 + (((kh * 4 + l4) ^ (cl & 7)) * 16)); \
    }

// One phase: sync + 16 MFMA on (AREG, bR) into acc[AH][BH]. Loads for the
// phase are issued by the caller BEFORE invoking PH (or carried in regs).
#define PH(AREG, AH, BH, STAGE_STMT, VM_STMT)                                  \
  {                                                                            \
    STAGE_STMT;                                                                \
    __builtin_amdgcn_s_barrier();                                              \
    asm volatile("s_waitcnt lgkmcnt(0)" ::: "memory");                         \
    __builtin_amdgcn_sched_barrier(0);                                         \
    __builtin_amdgcn_s_setprio(1);                                             \
    _Pragma("unroll")                                                          \
    for (int kh = 0; kh < 2; ++kh)                                             \
      _Pragma("unroll")                                                        \
      for (int mi = 0; mi < 2; ++mi)                                           \
        _Pragma("unroll")                                                      \
        for (int ni = 0; ni < 4; ++ni)                                         \
          acc[AH][BH][mi][ni] = __builtin_amdgcn_mfma_f32_16x16x32_bf16(       \
              AREG[kh][mi], bR[kh][ni], acc[AH][BH][mi][ni], 0, 0, 0);         \
    __builtin_amdgcn_s_setprio(0);                                             \
    __builtin_amdgcn_sched_barrier(0);                                         \
    VM_STMT;                                                                   \
    __builtin_amdgcn_s_barrier();                                              \
  }

__global__ __launch_bounds__(512, 1) void conv8_k(Job j0, Job j1) {
  extern __shared__ char smem[];
  // LDS map: A [dbuf2][half2][64 rows][128B] @0 (32KB)
  //          B [dbuf2][half2][256 f][128B] @32768 (128KB)  total 160KB
  const Job jb = (blockIdx.x >> 7) ? j1 : j0;
  const int inner = blockIdx.x & 127;
  const int swz = (inner & 7) * 16 + (inner >> 3);  // XCD bijective (128=8*16)
  const int b  = swz >> 2;             // 4 M-tiles per batch
  const int st = (swz & 3) * 128;
  const int t = threadIdx.x;
  const int lane = t & 63;
  const int wave = t >> 6;
  const int wm2 = wave >> 2;           // 2 M wave-groups
  const int wn  = wave & 3;            // 4 N wave-groups
  const int rA = lane & 15;
  const int l4 = lane >> 4;
  const int rowbase = 32 * wm2 + rA;   // local row within A-half
  const int colbase = 64 * wn + rA;    // local col within B-half

  f32x4 acc[2][2][2][4];               // [ah][bh][mi][ni]
  #pragma unroll
  for (int a = 0; a < 2; ++a)
    #pragma unroll
    for (int c = 0; c < 2; ++c)
      #pragma unroll
      for (int m = 0; m < 2; ++m)
        #pragma unroll
        for (int n = 0; n < 4; ++n) acc[a][c][m][n] = (f32x4){0.f, 0.f, 0.f, 0.f};

  // half-tile stagers (wave-uniform load counts: A=1/thread, B=4/thread).
  auto stageA = [&](int kt, int half) {
    const int r = t >> 3, ch = t & 7;
    const __hip_bfloat16* ga = jb.Pin +
        ((size_t)b * SP_ + st + half * 64 + r + (kt >> 3)) * D_ +
        (kt & 7) * 64 + (ch ^ (r & 7)) * 8;
    GLOAD(ga, (kt & 1) * 16384 + half * 8192 + t * 16);
  };
  auto stageB = [&](int kt, int half) {
    #pragma unroll
    for (int i = 0; i < 4; ++i) {
      const int c = t + i * 512;
      const int fr = c >> 3, ch = c & 7;
      const __hip_bfloat16* gb = jb.WT +
          (size_t)(half * 256 + fr) * KK_ + kt * 64 + (ch ^ (fr & 7)) * 8;
      GLOAD(gb, 32768 + (kt & 1) * 65536 + half * 32768 + c * 16);
    }
  };

  // Prologue: tile0 fully (10 loads), tile1.A0 + tile1.B1 (5). vmcnt(5) -> t0 landed.
  stageA(0, 0); stageB(0, 0); stageA(0, 1); stageB(0, 1);
  stageA(1, 0); stageB(1, 1);
  asm volatile("s_waitcnt vmcnt(5)" ::: "memory");
  __builtin_amdgcn_s_barrier();

  bf16x8 aR0[2][2], aR1[2][2], bR[2][4];

  for (int it = 0; it < NITER; ++it) {
    const int tk = 2 * it;             // even tile -> dbuf0, odd -> dbuf1
    const bool more = (it < NITER - 1);
    // ---- dbuf0, tile tk: ring A0B0 -> A1B0 -> A1B1 -> A0B1 ----
    LOADA(aR0, 0, 0); LOADB(0, 0);                       // 12 reads
    PH(aR0, 0, 0, { stageB(tk + 1, 0); }, );
    LOADA(aR1, 0, 1);                                    // 4 reads (carry bR=B0)
    PH(aR1, 1, 0, { stageA(tk + 1, 1); }, );
    LOADB(0, 1);                                         // 8 reads (carry aR1)
    PH(aR1, 1, 1, { if (more) stageA(tk + 2, 0); }, );
    // no reads: carry aR0 (from ph1) + bR (B1 from ph3)
    PH(aR0, 0, 1, { if (more) stageB(tk + 2, 1); },
       if (more) { asm volatile("s_waitcnt vmcnt(5)" ::: "memory"); }
       else      { asm volatile("s_waitcnt vmcnt(0)" ::: "memory"); });
    // ---- dbuf1, tile tk+1: same ring ----
    LOADA(aR0, 1, 0); LOADB(1, 0);
    PH(aR0, 0, 0, { if (more) stageB(tk + 2, 0); }, );
    LOADA(aR1, 1, 1);
    PH(aR1, 1, 0, { if (more) stageA(tk + 2, 1); }, );
    LOADB(1, 1);
    PH(aR1, 1, 1, { if (more) stageA(tk + 3, 0); }, );
    PH(aR0, 0, 1, { if (more) stageB(tk + 3, 1); },
       if (more) { asm volatile("s_waitcnt vmcnt(5)" ::: "memory"); }
       else      { asm volatile("s_waitcnt vmcnt(0)" ::: "memory"); });
  }

  // ---------------- fused epilogue: bias + relu + LN (+ linear) --------------
  float* rS = (float*)smem;            // [4 wn][128 rows]
  float* rQ = rS + 512;
  float* rP = rQ + 512;
  float* tS = rP + 512;                // [128]
  float* tQ = tS + 128;
  float* tP = tQ + 128;
  float* wG = tP + 128;                // [4]
  float* wB = wG + 4;

  const int MODE = jb.mode;
  float bia[2][4], gg[2][4], bb[2][4], ww[2][4];
  #pragma unroll
  for (int bh = 0; bh < 2; ++bh)
    #pragma unroll
    for (int ni = 0; ni < 4; ++ni) {
      const int f = 64 * wn + bh * 256 + 16 * ni + rA;
      bia[bh][ni] = jb.bias[f]; gg[bh][ni] = jb.g[f]; bb[bh][ni] = jb.be[f];
      ww[bh][ni] = (MODE == 1) ? jb.wl[f] : 0.f;
    }
  if (MODE == 1 && wm2 == 0) {
    float gwp = 0.f, bwp = 0.f;
    #pragma unroll
    for (int bh = 0; bh < 2; ++bh)
      #pragma unroll
      for (int ni = 0; ni < 4; ++ni) {
        gwp += gg[bh][ni] * ww[bh][ni]; bwp += bb[bh][ni] * ww[bh][ni];
      }
    #pragma unroll
    for (int o = 1; o < 16; o <<= 1) {
      gwp += __shfl_xor(gwp, o); bwp += __shfl_xor(bwp, o);
    }
    if (lane == 0) { wG[wn] = gwp; wB[wn] = bwp; }
  }
  #pragma unroll
  for (int ah = 0; ah < 2; ++ah)
    #pragma unroll
    for (int mi = 0; mi < 2; ++mi)
      #pragma unroll
      for (int reg = 0; reg < 4; ++reg) {
        float sv = 0.f, sq = 0.f, sp = 0.f;
        #pragma unroll
        for (int bh = 0; bh < 2; ++bh)
          #pragma unroll
          for (int ni = 0; ni < 4; ++ni) {
            float v = fmaxf(acc[ah][bh][mi][ni][reg] + bia[bh][ni], 0.f);
            acc[ah][bh][mi][ni][reg] = v;
            sv += v; sq += v * v;
            sp += v * gg[bh][ni] * ww[bh][ni];
          }
        #pragma unroll
        for (int o = 1; o < 16; o <<= 1) {
          sv += __shfl_xor(sv, o); sq += __shfl_xor(sq, o);
          sp += __shfl_xor(sp, o);
        }
        if (rA == 0) {
          const int lr = 64 * ah + 32 * wm2 + 16 * mi + l4 * 4 + reg;
          rS[wn * 128 + lr] = sv; rQ[wn * 128 + lr] = sq; rP[wn * 128 + lr] = sp;
        }
      }
  __syncthreads();
  if (t < 128) {
    float S = 0.f, Q = 0.f, Pp = 0.f;
    #pragma unroll
    for (int w = 0; w < 4; ++w) {
      S += rS[w * 128 + t]; Q += rQ[w * 128 + t]; Pp += rP[w * 128 + t];
    }
    tS[t] = S; tQ[t] = Q; tP[t] = Pp;
  }
  __syncthreads();
  if (MODE == 0) {
    unsigned short* Pu = (unsigned short*)jb.Pout;
    #pragma unroll
    for (int ah = 0; ah < 2; ++ah)
      #pragma unroll
      for (int mi = 0; mi < 2; ++mi)
        #pragma unroll
        for (int reg = 0; reg < 4; ++reg) {
          const int lr = 64 * ah + 32 * wm2 + 16 * mi + l4 * 4 + reg;
          const float mean = tS[lr] * (1.f / F_);
          const float var = tQ[lr] * (1.f / F_) - mean * mean;
          const float inv = rsqrtf(var + 1e-5f);
          unsigned short* pp = Pu + ((size_t)b * SP_ + st + lr + 1) * D_;
          #pragma unroll
          for (int bh = 0; bh < 2; ++bh)
            #pragma unroll
            for (int ni = 0; ni < 4; ++ni)
              pp[64 * wn + bh * 256 + 16 * ni + rA] =
                  f2bf((acc[ah][bh][mi][ni][reg] - mean) * inv * gg[bh][ni] + bb[bh][ni]);
        }
  } else {
    if (t < 128) {
      const float GW = wG[0] + wG[1] + wG[2] + wG[3];
      const float BW = wB[0] + wB[1] + wB[2] + wB[3];
      const float mean = tS[t] * (1.f / F_);
      const float var = tQ[t] * (1.f / F_) - mean * mean;
      const float inv = rsqrtf(var + 1e-5f);
      const int grow = b * S_ + st + t;
      jb.pred[grow] = jb.mask[grow] ? 0.f
                                    : (inv * tP[t] - inv * mean * GW + BW + jb.bl[0]);
    }
  }
}

// --- length regulate (2 positions/block) + mel_mask -> float folded in ------
__global__ __launch_bounds__(256) void gather_k(const __hip_bfloat16* __restrict__ X,
                                                const int* __restrict__ cum,
                                                const unsigned char* __restrict__ melm,
                                                float* __restrict__ out,
                                                float* __restrict__ maskf) {
  const int b    = blockIdx.x >> 11;
  const int pos0 = (blockIdx.x & 2047) * 2;
  const int half = threadIdx.x >> 7;
  const int tl   = threadIdx.x & 127;
  const int pos  = pos0 + half;
  __shared__ int sidx[2], svalid[2];
  if (tl == 0) {
    const int* c = cum + b * S_;
    int lo = 0, hi = S_;
    while (lo < hi) {
      const int mid = (lo + hi) >> 1;
      if (c[mid] <= pos) lo = mid + 1; else hi = mid;
    }
    sidx[half] = (lo < S_ - 1) ? lo : (S_ - 1);
    svalid[half] = (pos < c[S_ - 1]) ? 1 : 0;
    maskf[(size_t)b * T_ + pos] = melm[(size_t)b * T_ + pos] ? 1.f : 0.f;
  }
  __syncthreads();
  float4 v = make_float4(0.f, 0.f, 0.f, 0.f);
  if (svalid[half]) {
    const ushort4 u = *(const ushort4*)((const unsigned short*)X +
                        ((size_t)b * SP_ + sidx[half] + 1) * D_ + tl * 4);
    v = make_float4(bf2f(u.x), bf2f(u.y), bf2f(u.z), bf2f(u.w));
  }
  *(float4*)(out + ((size_t)b * T_ + pos) * D_ + tl * 4) = v;
}

extern "C" void kernel_launch(void* const* d_in, const int* in_sizes, int n_in,
                              void* d_out, int out_size, void* d_ws, size_t ws_size,
                              hipStream_t stream) {
  const float* x            = (const float*)d_in[0];
  const unsigned char* srcm = (const unsigned char*)d_in[1];
  const unsigned char* melm = (const unsigned char*)d_in[2];
  const float* pitch_truth  = (const float*)d_in[3];
  const float* energy_truth = (const float*)d_in[4];
  const int*   dur          = (const int*)d_in[5];
  const float* conv1_w = (const float*)d_in[6];
  const float* conv1_b = (const float*)d_in[7];
  const float* ln1_g   = (const float*)d_in[8];
  const float* ln1_b   = (const float*)d_in[9];
  const float* conv2_w = (const float*)d_in[10];
  const float* conv2_b = (const float*)d_in[11];
  const float* ln2_g   = (const float*)d_in[12];
  const float* ln2_b   = (const float*)d_in[13];
  const float* lin_w   = (const float*)d_in[14];
  const float* lin_b   = (const float*)d_in[15];
  const float* pitch_emb   = (const float*)d_in[16];
  const float* energy_emb  = (const float*)d_in[17];
  const float* pitch_bins  = (const float*)d_in[18];
  const float* energy_bins = (const float*)d_in[19];

  float* out      = (float*)d_out;
  float* x_out    = out;                               // 32*4096*512
  float* p_pitch  = out + (size_t)B_ * T_ * D_;
  float* p_energy = p_pitch + B_ * S_;
  float* p_dur    = p_energy + B_ * S_;
  float* p_mellen = p_dur + B_ * S_;
  float* p_mask   = p_mellen + B_;

  // ws slots (16.86MB padded bf16 each): S0=X0/P2, S1=X1, S2=X2, S3=P0, S4=P1
  // | WT1 WT2 (4.7MB each) | cum (64KB)   total ~93.7MB
  __hip_bfloat16* S0  = (__hip_bfloat16*)d_ws;
  __hip_bfloat16* S1  = S0 + SLOT;
  __hip_bfloat16* S2  = S1 + SLOT;
  __hip_bfloat16* S3  = S2 + SLOT;
  __hip_bfloat16* S4  = S3 + SLOT;
  __hip_bfloat16* WT1 = S4 + SLOT;
  __hip_bfloat16* WT2 = WT1 + (size_t)3 * F_ * KK_;
  int*  cum = (int*)(WT2 + (size_t)3 * F_ * KK_);

  const dim3 blk512t(512), blk256(256);
  const int convLds = 163840;                // 160 KB: full pool, 1 block/CU
  hipFuncSetAttribute((const void*)conv8_k,
                      hipFuncAttributeMaxDynamicSharedMemorySize, convLds);

  prep_k<<<dim3(WT_BLKS + TP_BLKS + B_), blk256, 0, stream>>>(
      x, conv1_w, conv2_w, dur, pitch_truth, pitch_bins, pitch_emb,
      energy_truth, energy_bins, energy_emb,
      S0, S1, S2, S3, S4, WT1, WT2, cum, p_mellen);

  auto c1 = [&](int i, const __hip_bfloat16* in, __hip_bfloat16* Pout) {
    return Job{in, WT1 + (size_t)i * F_ * KK_, conv1_b + (size_t)i * F_,
               ln1_g + (size_t)i * F_, ln1_b + (size_t)i * F_,
               nullptr, nullptr, nullptr, Pout, nullptr, 0};
  };
  auto c2 = [&](int i, const __hip_bfloat16* in, float* pred) {
    return Job{in, WT2 + (size_t)i * F_ * KK_, conv2_b + (size_t)i * F_,
               ln2_g + (size_t)i * F_, ln2_b + (size_t)i * F_,
               lin_w + (size_t)i * F_, lin_b + i, srcm, nullptr, pred, 1};
  };

  // D1: conv1[0], conv1[1]   (256 blocks = 1/CU)
  {
    Job a = c1(0, S0, S3), b = c1(1, S1, S4);
    conv8_k<<<dim3(256), blk512t, convLds, stream>>>(a, b);
  }
  // D2: conv2[0], conv1[2]   (P2 reuses S0 — X0 fully consumed in D1)
  {
    Job a = c2(0, S3, p_pitch), b = c1(2, S2, S0);
    conv8_k<<<dim3(256), blk512t, convLds, stream>>>(a, b);
  }
  // D3: conv2[1], conv2[2]
  {
    Job a = c2(1, S4, p_energy), b = c2(2, S0, p_dur);
    conv8_k<<<dim3(256), blk512t, convLds, stream>>>(a, b);
  }

  gather_k<<<dim3(B_ * T_ / 2), blk256, 0, stream>>>(S2, cum, melm, x_out, p_mask);
}